// Round 1
// baseline (13116.946 us; speedup 1.0000x reference)
//
#include <hip/hip_runtime.h>
#include <hip/hip_bf16.h>

// Broadcast lane k's value to all lanes (k is unrolled-constant or uniform).
__device__ __forceinline__ float rl(float v, int k) {
  return __int_as_float(__builtin_amdgcn_readlane(__float_as_int(v), k));
}

// h_init[n] = mean_s(embed[tok[n,s]]) @ proj_W ; also copy into h.
__global__ __launch_bounds__(256) void k_embed_proj(
    const int* __restrict__ toks, const float* __restrict__ embed,
    const float* __restrict__ projW, float* __restrict__ h_init,
    float* __restrict__ h, int N) {
  __shared__ float sW[4096];
  int tid = threadIdx.x;
  for (int i = tid * 4; i < 4096; i += 1024)
    *(float4*)&sW[i] = *(const float4*)&projW[i];
  __syncthreads();
  int w = tid >> 6, lane = tid & 63;
  for (int n = blockIdx.x * 4 + w; n < N; n += gridDim.x * 4) {
    float acc = 0.f;
#pragma unroll
    for (int s = 0; s < 5; ++s) {
      int tok = toks[n * 5 + s];
      acc += embed[tok * 64 + lane];
    }
    float e = acc * 0.2f;
    float o = 0.f;
#pragma unroll
    for (int k = 0; k < 64; ++k) o += rl(e, k) * sW[k * 64 + lane];
    h_init[n * 64 + lane] = o;
    h[n * 64 + lane] = o;
  }
}

// CSR build: count incoming edges per dst over all 8 effective types.
__global__ void k_counts(const int* __restrict__ adj, int* __restrict__ counts, int E) {
  int e = blockIdx.x * 256 + threadIdx.x;
  if (e >= E) return;
  int t = blockIdx.y, t4 = t & 3;
  int a = adj[(t4 * E + e) * 2], b = adj[(t4 * E + e) * 2 + 1];
  int dst = (t < 4) ? b : a;
  atomicAdd(&counts[dst], 1);
}

// Single-block exclusive scan over N counts -> offsets[0..N].
__global__ __launch_bounds__(1024) void k_scan(const int* __restrict__ counts,
                                               int* __restrict__ offsets, int n) {
  __shared__ int part[1024];
  int tid = threadIdx.x;
  int chunk = (n + 1023) >> 10;
  int begin = tid * chunk, end = min(begin + chunk, n);
  int s = 0;
  for (int i = begin; i < end; ++i) s += counts[i];
  part[tid] = s;
  __syncthreads();
  for (int off = 1; off < 1024; off <<= 1) {
    int v = (tid >= off) ? part[tid - off] : 0;
    __syncthreads();
    part[tid] += v;
    __syncthreads();
  }
  int run = part[tid] - s;  // exclusive prefix
  for (int i = begin; i < end; ++i) { offsets[i] = run; run += counts[i]; }
  if (tid == 1023) offsets[n] = part[1023];
}

// Scatter edge entries (value = t*N + src) into CSR slots.
__global__ void k_fill(const int* __restrict__ adj, int* __restrict__ cursor,
                       int* __restrict__ entries, int E, int N) {
  int e = blockIdx.x * 256 + threadIdx.x;
  if (e >= E) return;
  int t = blockIdx.y, t4 = t & 3;
  int a = adj[(t4 * E + e) * 2], b = adj[(t4 * E + e) * 2 + 1];
  int src = (t < 4) ? a : b;
  int dst = (t < 4) ? b : a;
  int pos = atomicAdd(&cursor[dst], 1);
  entries[pos] = t * N + src;
}

// Ht[t][n] = h[n] @ W[t]  (8 GEMMs, one wave handles 4 nodes).
__global__ __launch_bounds__(256) void k_transform(
    const float* __restrict__ h, const float* __restrict__ W8,
    float* __restrict__ Ht, int N) {
  __shared__ float sW[4096];
  int tid = threadIdx.x;
  const float* W = W8 + blockIdx.y * 4096;
  for (int i = tid * 4; i < 4096; i += 1024)
    *(float4*)&sW[i] = *(const float4*)&W[i];
  __syncthreads();
  int w = tid >> 6, lane = tid & 63;
  int tN = blockIdx.y * N;
  for (int n0 = (blockIdx.x * 4 + w) * 4; n0 < N; n0 += gridDim.x * 16) {
    if (n0 + 4 <= N) {
      float h0 = h[(n0 + 0) * 64 + lane];
      float h1 = h[(n0 + 1) * 64 + lane];
      float h2 = h[(n0 + 2) * 64 + lane];
      float h3 = h[(n0 + 3) * 64 + lane];
      float a0 = 0.f, a1 = 0.f, a2 = 0.f, a3 = 0.f;
#pragma unroll
      for (int k = 0; k < 64; ++k) {
        float wv = sW[k * 64 + lane];
        a0 += rl(h0, k) * wv;
        a1 += rl(h1, k) * wv;
        a2 += rl(h2, k) * wv;
        a3 += rl(h3, k) * wv;
      }
      int base = (tN + n0) * 64 + lane;
      Ht[base] = a0; Ht[base + 64] = a1; Ht[base + 128] = a2; Ht[base + 192] = a3;
    } else {
      for (int n = n0; n < N; ++n) {
        float hv = h[n * 64 + lane];
        float a = 0.f;
#pragma unroll
        for (int k = 0; k < 64; ++k) a += rl(hv, k) * sW[k * 64 + lane];
        Ht[(tN + n) * 64 + lane] = a;
      }
    }
  }
}

// msg[n] = max over incoming edges of Ht[entry]; 0 if no edges.
__global__ __launch_bounds__(256) void k_aggmax(
    const float* __restrict__ Ht, const int* __restrict__ offsets,
    const int* __restrict__ entries, float* __restrict__ msg, int N) {
  int w = threadIdx.x >> 6, lane = threadIdx.x & 63;
  int n = blockIdx.x * 4 + w;
  if (n >= N) return;
  int beg = offsets[n], end = offsets[n + 1];
  float m = -3.4e38f;
  int i = beg;
  for (; i + 2 <= end; i += 2) {
    int i0 = entries[i], i1 = entries[i + 1];
    float v0 = Ht[i0 * 64 + lane];
    float v1 = Ht[i1 * 64 + lane];
    m = fmaxf(m, fmaxf(v0, v1));
  }
  if (i < end) m = fmaxf(m, Ht[entries[i] * 64 + lane]);
  msg[n * 64 + lane] = (end > beg) ? m : 0.f;
}

__device__ __forceinline__ float sigmoidf_(float x) {
  return 1.f / (1.f + __expf(-x));
}
__device__ __forceinline__ float tanhf_(float x) {
  x = fminf(fmaxf(x, -20.f), 20.f);
  float e2 = __expf(2.f * x);
  return (e2 - 1.f) / (e2 + 1.f);
}

// Layer-0 GRU: h = GRU(x=msg, h). In-place per-node update.
__global__ __launch_bounds__(1024) void k_gru0(
    const float* __restrict__ x, float* __restrict__ h,
    const float* __restrict__ Wx, const float* __restrict__ Wh,
    const float* __restrict__ b, int N) {
  __shared__ float sWx[64 * 192];
  __shared__ float sWh[64 * 192];
  int tid = threadIdx.x;
  for (int i = tid * 4; i < 64 * 192; i += 4096) {
    *(float4*)&sWx[i] = *(const float4*)&Wx[i];
    *(float4*)&sWh[i] = *(const float4*)&Wh[i];
  }
  __syncthreads();
  int w = tid >> 6, lane = tid & 63;
  float br = b[lane], bu = b[64 + lane], bc = b[128 + lane];
  for (int n = blockIdx.x * 16 + w; n < N; n += gridDim.x * 16) {
    float xv = x[n * 64 + lane], hv = h[n * 64 + lane];
    float ar = br, au = bu, ac = bc, hr = 0.f, hu = 0.f, hc = 0.f;
#pragma unroll
    for (int k = 0; k < 64; ++k) {
      float xk = rl(xv, k), hk = rl(hv, k);
      ar += xk * sWx[k * 192 + lane];
      au += xk * sWx[k * 192 + 64 + lane];
      ac += xk * sWx[k * 192 + 128 + lane];
      hr += hk * sWh[k * 192 + lane];
      hu += hk * sWh[k * 192 + 64 + lane];
      hc += hk * sWh[k * 192 + 128 + lane];
    }
    float r = sigmoidf_(ar + hr);
    float u = sigmoidf_(au + hu);
    float c = tanhf_(ac + r * hc);
    h[n * 64 + lane] = u * hv + (1.f - u) * c;
  }
}

// Layer-1 GRU: x = concat(h_init, msg), Wx is [128,192]; writes d_out.
__global__ __launch_bounds__(1024) void k_gru1(
    const float* __restrict__ hinit, const float* __restrict__ msg,
    const float* __restrict__ h, const float* __restrict__ Wx,
    const float* __restrict__ Wh, const float* __restrict__ b,
    float* __restrict__ out, int N) {
  __shared__ float sWx[128 * 192];
  __shared__ float sWh[64 * 192];
  int tid = threadIdx.x;
  for (int i = tid * 4; i < 128 * 192; i += 4096)
    *(float4*)&sWx[i] = *(const float4*)&Wx[i];
  for (int i = tid * 4; i < 64 * 192; i += 4096)
    *(float4*)&sWh[i] = *(const float4*)&Wh[i];
  __syncthreads();
  int w = tid >> 6, lane = tid & 63;
  float br = b[lane], bu = b[64 + lane], bc = b[128 + lane];
  for (int n = blockIdx.x * 16 + w; n < N; n += gridDim.x * 16) {
    float xi = hinit[n * 64 + lane];
    float xm = msg[n * 64 + lane];
    float hv = h[n * 64 + lane];
    float ar = br, au = bu, ac = bc, hr = 0.f, hu = 0.f, hc = 0.f;
#pragma unroll
    for (int k = 0; k < 64; ++k) {
      float xk = rl(xi, k);
      ar += xk * sWx[k * 192 + lane];
      au += xk * sWx[k * 192 + 64 + lane];
      ac += xk * sWx[k * 192 + 128 + lane];
    }
#pragma unroll
    for (int k = 0; k < 64; ++k) {
      float xk = rl(xm, k);
      ar += xk * sWx[(64 + k) * 192 + lane];
      au += xk * sWx[(64 + k) * 192 + 64 + lane];
      ac += xk * sWx[(64 + k) * 192 + 128 + lane];
    }
#pragma unroll
    for (int k = 0; k < 64; ++k) {
      float hk = rl(hv, k);
      hr += hk * sWh[k * 192 + lane];
      hu += hk * sWh[k * 192 + 64 + lane];
      hc += hk * sWh[k * 192 + 128 + lane];
    }
    float r = sigmoidf_(ar + hr);
    float u = sigmoidf_(au + hu);
    float c = tanhf_(ac + r * hc);
    out[n * 64 + lane] = u * hv + (1.f - u) * c;
  }
}

extern "C" void kernel_launch(void* const* d_in, const int* in_sizes, int n_in,
                              void* d_out, int out_size, void* d_ws, size_t ws_size,
                              hipStream_t stream) {
  const int*   toks  = (const int*)d_in[0];
  const int*   adj   = (const int*)d_in[1];
  const float* embed = (const float*)d_in[2];
  const float* projW = (const float*)d_in[3];
  const float* eW0   = (const float*)d_in[4];
  const float* eW1   = (const float*)d_in[5];
  const float* g0Wx  = (const float*)d_in[6];
  const float* g0Wh  = (const float*)d_in[7];
  const float* g0b   = (const float*)d_in[8];
  const float* g1Wx  = (const float*)d_in[9];
  const float* g1Wh  = (const float*)d_in[10];
  const float* g1b   = (const float*)d_in[11];
  float* out = (float*)d_out;

  int N = in_sizes[0] / 5;   // nodes
  int E = in_sizes[1] / 8;   // edges per primary type (T=4, 2 cols)

  char* p = (char*)d_ws;
  float* h      = (float*)p; p += (size_t)N * 64 * sizeof(float);
  float* h_init = (float*)p; p += (size_t)N * 64 * sizeof(float);
  float* msg    = (float*)p; p += (size_t)N * 64 * sizeof(float);
  float* Ht     = (float*)p; p += (size_t)8 * N * 64 * sizeof(float);
  int* counts   = (int*)p;   p += (size_t)(N + 64) * sizeof(int);
  int* offsets  = (int*)p;   p += (size_t)(N + 64) * sizeof(int);
  int* cursor   = (int*)p;   p += (size_t)(N + 64) * sizeof(int);
  int* entries  = (int*)p;   p += (size_t)8 * E * sizeof(int);
  if ((size_t)(p - (char*)d_ws) > ws_size) return;  // ws too small: fail loudly

  hipMemsetAsync(counts, 0, (size_t)N * sizeof(int), stream);
  k_embed_proj<<<512, 256, 0, stream>>>(toks, embed, projW, h_init, h, N);

  dim3 egrid((E + 255) / 256, 8);
  k_counts<<<egrid, 256, 0, stream>>>(adj, counts, E);
  k_scan<<<1, 1024, 0, stream>>>(counts, offsets, N);
  hipMemcpyAsync(cursor, offsets, (size_t)N * sizeof(int),
                 hipMemcpyDeviceToDevice, stream);
  k_fill<<<egrid, 256, 0, stream>>>(adj, cursor, entries, E, N);

  dim3 tgrid(240, 8);
  int agrid = (N + 3) / 4;
  for (int it = 0; it < 7; ++it) {
    k_transform<<<tgrid, 256, 0, stream>>>(h, eW0, Ht, N);
    k_aggmax<<<agrid, 256, 0, stream>>>(Ht, offsets, entries, msg, N);
    k_gru0<<<256, 1024, 0, stream>>>(msg, h, g0Wx, g0Wh, g0b, N);
  }
  k_transform<<<tgrid, 256, 0, stream>>>(h, eW1, Ht, N);
  k_aggmax<<<agrid, 256, 0, stream>>>(Ht, offsets, entries, msg, N);
  k_gru1<<<256, 1024, 0, stream>>>(h_init, msg, h, g1Wx, g1Wh, g1b, out, N);
}

// Round 2
// 1596.076 us; speedup vs baseline: 8.2182x; 8.2182x over previous
//
#include <hip/hip_runtime.h>
#include <hip/hip_bf16.h>

// ---------- small helpers ----------
__device__ __forceinline__ float sigmoidf_(float x) {
  return 1.f / (1.f + __expf(-x));
}
__device__ __forceinline__ float tanhf_(float x) {
  x = fminf(fmaxf(x, -20.f), 20.f);
  float e2 = __expf(2.f * x);
  return (e2 - 1.f) / (e2 + 1.f);
}

// ---------- embedding gather: emb[n] = mean_s embed[tok[n,s]] ----------
__global__ __launch_bounds__(256) void k_embed(
    const int* __restrict__ toks, const float* __restrict__ embed,
    float* __restrict__ emb, int N) {
  int w = threadIdx.x >> 6, lane = threadIdx.x & 63;
  for (int n = blockIdx.x * 4 + w; n < N; n += gridDim.x * 4) {
    float acc = 0.f;
#pragma unroll
    for (int s = 0; s < 5; ++s)
      acc += embed[(size_t)toks[n * 5 + s] * 64 + lane];
    emb[(size_t)n * 64 + lane] = acc * 0.2f;
  }
}

// ---------- CSR build ----------
__global__ void k_counts(const int* __restrict__ adj, int* __restrict__ counts, int E) {
  int e = blockIdx.x * 256 + threadIdx.x;
  if (e >= E) return;
  int t = blockIdx.y, t4 = t & 3;
  int a = adj[(size_t)(t4 * E + e) * 2], b = adj[(size_t)(t4 * E + e) * 2 + 1];
  int dst = (t < 4) ? b : a;
  atomicAdd(&counts[dst], 1);
}

__global__ __launch_bounds__(1024) void k_scan(const int* __restrict__ counts,
                                               int* __restrict__ offsets, int n) {
  __shared__ int part[1024];
  int tid = threadIdx.x;
  int chunk = (n + 1023) >> 10;
  int begin = tid * chunk, end = min(begin + chunk, n);
  int s = 0;
  for (int i = begin; i < end; ++i) s += counts[i];
  part[tid] = s;
  __syncthreads();
  for (int off = 1; off < 1024; off <<= 1) {
    int v = (tid >= off) ? part[tid - off] : 0;
    __syncthreads();
    part[tid] += v;
    __syncthreads();
  }
  int run = part[tid] - s;
  for (int i = begin; i < end; ++i) { offsets[i] = run; run += counts[i]; }
  if (tid == 1023) offsets[n] = part[1023];
}

__global__ void k_fill(const int* __restrict__ adj, int* __restrict__ cursor,
                       int* __restrict__ entries, int E, int N) {
  int e = blockIdx.x * 256 + threadIdx.x;
  if (e >= E) return;
  int t = blockIdx.y, t4 = t & 3;
  int a = adj[(size_t)(t4 * E + e) * 2], b = adj[(size_t)(t4 * E + e) * 2 + 1];
  int src = (t < 4) ? a : b;
  int dst = (t < 4) ? b : a;
  int pos = atomicAdd(&cursor[dst], 1);
  entries[pos] = t * N + src;
}

// ---------- generic tiled GEMM: C[m][jt+j] = sum_k A[m][k]*W[k][jt+j] (+bias) ----------
// A = concat(A0, A1) along k (A1 optional, 64 each). Tile: 128 rows x 64 cols.
// 256 threads, each 8 rows x 4 cols. tmode: blockIdx.y selects edge type
// (W += y*4096, C += y*N*64); else blockIdx.y is the 64-wide column tile.
__global__ __launch_bounds__(256) void k_gemm(
    const float* __restrict__ A0, const float* __restrict__ A1,
    const float* __restrict__ W, int ldw, const float* __restrict__ bias,
    float* __restrict__ C, float* __restrict__ C2, int ldc, int N, int tmode) {
  __shared__ float aT[64 * 128];  // [k][m]
  __shared__ float sW[64 * 64];   // [k][j]
  int tid = threadIdx.x;
  const float* Wb = W;
  float* Cb = C;
  int jt = 0;
  if (tmode) {
    Wb = W + (size_t)blockIdx.y * 64 * 64;
    Cb = C + (size_t)blockIdx.y * N * 64;
  } else {
    jt = blockIdx.y * 64;
  }
  int m_base = blockIdx.x * 128;
  int r = tid >> 4, c = tid & 15;  // r: 0..15 (8 rows each), c: 0..15 (4 cols each)
  float acc[8][4] = {};
  int nkt = A1 ? 2 : 1;
  for (int kt = 0; kt < nkt; ++kt) {
    if (kt) __syncthreads();
    const float* A = kt ? A1 : A0;
    // stage A^T: aT[k][m]
    {
      int m = tid & 127, half = tid >> 7;
      int mm = min(m_base + m, N - 1);
      const float* src = &A[(size_t)mm * 64 + half * 32];
#pragma unroll
      for (int q = 0; q < 8; ++q) {
        float4 v = *(const float4*)(src + q * 4);
        int d0 = half * 32 + q * 4;
        aT[(d0 + 0) * 128 + m] = v.x;
        aT[(d0 + 1) * 128 + m] = v.y;
        aT[(d0 + 2) * 128 + m] = v.z;
        aT[(d0 + 3) * 128 + m] = v.w;
      }
    }
    // stage W tile: sW[k][j], rows kt*64.., cols jt..jt+63
    {
#pragma unroll
      for (int q = 0; q < 4; ++q) {
        int idx = q * 256 + tid;
        int k = idx >> 4, j4 = (idx & 15) * 4;
        *(float4*)&sW[k * 64 + j4] =
            *(const float4*)&Wb[(size_t)(kt * 64 + k) * ldw + jt + j4];
      }
    }
    __syncthreads();
#pragma unroll 8
    for (int k = 0; k < 64; ++k) {
      float4 a0 = *(const float4*)&aT[k * 128 + r * 8];
      float4 a1 = *(const float4*)&aT[k * 128 + r * 8 + 4];
      float4 wv = *(const float4*)&sW[k * 64 + c * 4];
      float av[8] = {a0.x, a0.y, a0.z, a0.w, a1.x, a1.y, a1.z, a1.w};
#pragma unroll
      for (int i = 0; i < 8; ++i) {
        acc[i][0] += av[i] * wv.x;
        acc[i][1] += av[i] * wv.y;
        acc[i][2] += av[i] * wv.z;
        acc[i][3] += av[i] * wv.w;
      }
    }
  }
  float4 bv = {0.f, 0.f, 0.f, 0.f};
  if (bias) bv = *(const float4*)&bias[jt + c * 4];
#pragma unroll
  for (int i = 0; i < 8; ++i) {
    int m = m_base + r * 8 + i;
    if (m < N) {
      float4 o = {acc[i][0] + bv.x, acc[i][1] + bv.y,
                  acc[i][2] + bv.z, acc[i][3] + bv.w};
      *(float4*)&Cb[(size_t)m * ldc + jt + c * 4] = o;
      if (C2) *(float4*)&C2[(size_t)m * ldc + jt + c * 4] = o;
    }
  }
}

// ---------- msg[n] = segment-max of Ht over incoming edges ----------
__global__ __launch_bounds__(256) void k_aggmax(
    const float* __restrict__ Ht, const int* __restrict__ offsets,
    const int* __restrict__ entries, float* __restrict__ msg, int N) {
  int w = threadIdx.x >> 6, lane = threadIdx.x & 63;
  int n = blockIdx.x * 4 + w;
  if (n >= N) return;
  int beg = offsets[n], end = offsets[n + 1];
  float m = -3.4e38f;
  int i = beg;
  for (; i + 4 <= end; i += 4) {
    int i0 = entries[i], i1 = entries[i + 1], i2 = entries[i + 2], i3 = entries[i + 3];
    float v0 = Ht[(size_t)i0 * 64 + lane];
    float v1 = Ht[(size_t)i1 * 64 + lane];
    float v2 = Ht[(size_t)i2 * 64 + lane];
    float v3 = Ht[(size_t)i3 * 64 + lane];
    m = fmaxf(m, fmaxf(fmaxf(v0, v1), fmaxf(v2, v3)));
  }
  for (; i < end; ++i) m = fmaxf(m, Ht[(size_t)entries[i] * 64 + lane]);
  msg[(size_t)n * 64 + lane] = (end > beg) ? m : 0.f;
}

// ---------- fused gh-GEMM + GRU gates ----------
// gh = h@Wh (Wh [64][192] LDS-resident); gates from gx buffer; writes hout.
// Tile: 64 rows; 256 threads, each 4 rows x 4 cols x 3 gate sections.
__global__ __launch_bounds__(256) void k_gruh(
    const float* __restrict__ h, const float* __restrict__ gx,
    const float* __restrict__ Wh, float* __restrict__ hout, int N) {
  __shared__ float aT[64 * 64];    // h^T [k][m]
  __shared__ float sW[64 * 192];   // Wh [k][j]
  int tid = threadIdx.x;
  int m_base = blockIdx.x * 64;
  // stage h^T
  {
    int m = tid & 63, w = tid >> 6;
    int mm = min(m_base + m, N - 1);
    const float* src = &h[(size_t)mm * 64 + w * 16];
#pragma unroll
    for (int q = 0; q < 4; ++q) {
      float4 v = *(const float4*)(src + q * 4);
      int d0 = w * 16 + q * 4;
      aT[(d0 + 0) * 64 + m] = v.x;
      aT[(d0 + 1) * 64 + m] = v.y;
      aT[(d0 + 2) * 64 + m] = v.z;
      aT[(d0 + 3) * 64 + m] = v.w;
    }
  }
  // stage Wh (flat copy, same layout)
  for (int i = tid * 4; i < 64 * 192; i += 1024)
    *(float4*)&sW[i] = *(const float4*)&Wh[i];
  __syncthreads();
  int r = tid >> 4, c = tid & 15;
  int j4 = c * 4;
  float accR[4][4] = {}, accU[4][4] = {}, accC[4][4] = {};
#pragma unroll 4
  for (int k = 0; k < 64; ++k) {
    float4 a = *(const float4*)&aT[k * 64 + r * 4];
    float4 wr = *(const float4*)&sW[k * 192 + j4];
    float4 wu = *(const float4*)&sW[k * 192 + 64 + j4];
    float4 wc = *(const float4*)&sW[k * 192 + 128 + j4];
    float av[4] = {a.x, a.y, a.z, a.w};
#pragma unroll
    for (int i = 0; i < 4; ++i) {
      accR[i][0] += av[i] * wr.x; accR[i][1] += av[i] * wr.y;
      accR[i][2] += av[i] * wr.z; accR[i][3] += av[i] * wr.w;
      accU[i][0] += av[i] * wu.x; accU[i][1] += av[i] * wu.y;
      accU[i][2] += av[i] * wu.z; accU[i][3] += av[i] * wu.w;
      accC[i][0] += av[i] * wc.x; accC[i][1] += av[i] * wc.y;
      accC[i][2] += av[i] * wc.z; accC[i][3] += av[i] * wc.w;
    }
  }
#pragma unroll
  for (int i = 0; i < 4; ++i) {
    int m = m_base + r * 4 + i;
    if (m < N) {
      float4 gr = *(const float4*)&gx[(size_t)m * 192 + j4];
      float4 gu = *(const float4*)&gx[(size_t)m * 192 + 64 + j4];
      float4 gc = *(const float4*)&gx[(size_t)m * 192 + 128 + j4];
      float4 hv = *(const float4*)&h[(size_t)m * 64 + j4];
      const float* grp = &gr.x; const float* gup = &gu.x;
      const float* gcp = &gc.x; const float* hvp = &hv.x;
      float4 o;
      float* op = &o.x;
#pragma unroll
      for (int j = 0; j < 4; ++j) {
        float rr = sigmoidf_(grp[j] + accR[i][j]);
        float uu = sigmoidf_(gup[j] + accU[i][j]);
        float cc = tanhf_(gcp[j] + rr * accC[i][j]);
        op[j] = uu * hvp[j] + (1.f - uu) * cc;
      }
      *(float4*)&hout[(size_t)m * 64 + j4] = o;
    }
  }
}

extern "C" void kernel_launch(void* const* d_in, const int* in_sizes, int n_in,
                              void* d_out, int out_size, void* d_ws, size_t ws_size,
                              hipStream_t stream) {
  const int*   toks  = (const int*)d_in[0];
  const int*   adj   = (const int*)d_in[1];
  const float* embed = (const float*)d_in[2];
  const float* projW = (const float*)d_in[3];
  const float* eW0   = (const float*)d_in[4];
  const float* eW1   = (const float*)d_in[5];
  const float* g0Wx  = (const float*)d_in[6];
  const float* g0Wh  = (const float*)d_in[7];
  const float* g0b   = (const float*)d_in[8];
  const float* g1Wx  = (const float*)d_in[9];
  const float* g1Wh  = (const float*)d_in[10];
  const float* g1b   = (const float*)d_in[11];
  float* out = (float*)d_out;

  int N = in_sizes[0] / 5;
  int E = in_sizes[1] / 8;

  char* p = (char*)d_ws;
  float* h      = (float*)p; p += (size_t)N * 64 * sizeof(float);
  float* h_init = (float*)p; p += (size_t)N * 64 * sizeof(float);
  float* msg    = (float*)p; p += (size_t)N * 64 * sizeof(float);
  float* Ht     = (float*)p; p += (size_t)8 * N * 64 * sizeof(float);
  int* counts   = (int*)p;   p += (size_t)(N + 64) * sizeof(int);
  int* offsets  = (int*)p;   p += (size_t)(N + 64) * sizeof(int);
  int* cursor   = (int*)p;   p += (size_t)(N + 64) * sizeof(int);
  int* entries  = (int*)p;   p += (size_t)8 * E * sizeof(int);
  if ((size_t)(p - (char*)d_ws) > ws_size) return;
  // gx gate buffer [N][192] and emb [N][64] alias the Ht region (disjoint in time)
  float* gbuf = Ht;
  float* emb  = Ht;

  int g128 = (N + 127) / 128;
  int g64  = (N + 63) / 64;

  hipMemsetAsync(counts, 0, (size_t)N * sizeof(int), stream);
  k_embed<<<1024, 256, 0, stream>>>(toks, embed, emb, N);
  // h_init = emb @ projW ; h = h_init
  k_gemm<<<dim3(g128, 1), 256, 0, stream>>>(emb, nullptr, projW, 64, nullptr,
                                            h_init, h, 64, N, 0);
  dim3 egrid((E + 255) / 256, 8);
  k_counts<<<egrid, 256, 0, stream>>>(adj, counts, E);
  k_scan<<<1, 1024, 0, stream>>>(counts, offsets, N);
  hipMemcpyAsync(cursor, offsets, (size_t)N * sizeof(int),
                 hipMemcpyDeviceToDevice, stream);
  k_fill<<<egrid, 256, 0, stream>>>(adj, cursor, entries, E, N);

  int agrid = (N + 3) / 4;
  for (int it = 0; it < 7; ++it) {
    k_gemm<<<dim3(g128, 8), 256, 0, stream>>>(h, nullptr, eW0, 64, nullptr,
                                              Ht, nullptr, 64, N, 1);
    k_aggmax<<<agrid, 256, 0, stream>>>(Ht, offsets, entries, msg, N);
    k_gemm<<<dim3(g128, 3), 256, 0, stream>>>(msg, nullptr, g0Wx, 192, g0b,
                                              gbuf, nullptr, 192, N, 0);
    k_gruh<<<g64, 256, 0, stream>>>(h, gbuf, g0Wh, h, N);
  }
  k_gemm<<<dim3(g128, 8), 256, 0, stream>>>(h, nullptr, eW1, 64, nullptr,
                                            Ht, nullptr, 64, N, 1);
  k_aggmax<<<agrid, 256, 0, stream>>>(Ht, offsets, entries, msg, N);
  k_gemm<<<dim3(g128, 3), 256, 0, stream>>>(h_init, msg, g1Wx, 192, g1b,
                                            gbuf, nullptr, 192, N, 0);
  k_gruh<<<g64, 256, 0, stream>>>(h, gbuf, g1Wh, out, N);
}

// Round 3
// 1576.978 us; speedup vs baseline: 8.3178x; 1.0121x over previous
//
#include <hip/hip_runtime.h>

typedef short v8s __attribute__((ext_vector_type(8)));
typedef float v4f __attribute__((ext_vector_type(4)));

__device__ __forceinline__ unsigned short f2bf(float x) {
  unsigned u = __float_as_uint(x);
  u = u + 0x7FFFu + ((u >> 16) & 1u);
  return (unsigned short)(u >> 16);
}
__device__ __forceinline__ float bf2f(unsigned short b) {
  return __uint_as_float(((unsigned)b) << 16);
}
__device__ __forceinline__ float sigmoidf_(float x) {
  return 1.f / (1.f + __expf(-x));
}
__device__ __forceinline__ float tanhf_(float x) {
  x = fminf(fmaxf(x, -20.f), 20.f);
  float e2 = __expf(2.f * x);
  return (e2 - 1.f) / (e2 + 1.f);
}

// ---------- embedding gather -> bf16 hi/lo planes ----------
__global__ __launch_bounds__(256) void k_embed(
    const int* __restrict__ toks, const float* __restrict__ embed,
    unsigned short* __restrict__ eh, unsigned short* __restrict__ el, int N) {
  int w = threadIdx.x >> 6, lane = threadIdx.x & 63;
  int n = blockIdx.x * 4 + w;
  if (n >= N) return;
  float acc = 0.f;
#pragma unroll
  for (int s = 0; s < 5; ++s)
    acc += embed[(size_t)toks[n * 5 + s] * 64 + lane];
  float v = acc * 0.2f;
  unsigned short h = f2bf(v);
  eh[(size_t)n * 64 + lane] = h;
  el[(size_t)n * 64 + lane] = f2bf(v - bf2f(h));
}

// ---------- weight prep: f32 [T,K,J] -> frag-ready bf16 hi/lo ----------
// layout: idx = (((t*2+p)*nkc + kc)*nct + ct)*512 + lane*8 + j
// value:  W[t][kc*32 + (lane>>4)*8 + j][ct*16 + (lane&15)], p=0 hi, p=1 lo
__global__ void k_wprep(const float* __restrict__ W, unsigned short* __restrict__ Wf,
                        int K, int J, int total) {
  int idx = blockIdx.x * 256 + threadIdx.x;
  if (idx >= total) return;
  int nkc = K >> 5, nct = J >> 4;
  int j = idx & 7, lane = (idx >> 3) & 63;
  int rest = idx >> 9;
  int ct = rest % nct; rest /= nct;
  int kc = rest % nkc; rest /= nkc;
  int p = rest & 1, t = rest >> 1;
  int row = kc * 32 + (lane >> 4) * 8 + j;
  int col = ct * 16 + (lane & 15);
  float v = W[(size_t)t * K * J + (size_t)row * J + col];
  unsigned short hi = f2bf(v);
  Wf[idx] = p ? f2bf(v - bf2f(hi)) : hi;
}

// ---------- f32 -> two bf16 hi/lo pairs ----------
__global__ void k_split(const float* __restrict__ src,
                        unsigned short* __restrict__ h1, unsigned short* __restrict__ l1,
                        unsigned short* h2, unsigned short* l2, int total) {
  int i = (blockIdx.x * 256 + threadIdx.x) * 4;
  if (i >= total) return;
  float4 v = *(const float4*)&src[i];
  ushort4 hh, ll;
  hh.x = f2bf(v.x); ll.x = f2bf(v.x - bf2f(hh.x));
  hh.y = f2bf(v.y); ll.y = f2bf(v.y - bf2f(hh.y));
  hh.z = f2bf(v.z); ll.z = f2bf(v.z - bf2f(hh.z));
  hh.w = f2bf(v.w); ll.w = f2bf(v.w - bf2f(hh.w));
  *(ushort4*)&h1[i] = hh; *(ushort4*)&l1[i] = ll;
  if (h2) { *(ushort4*)&h2[i] = hh; *(ushort4*)&l2[i] = ll; }
}

// ---------- CSR build ----------
__global__ void k_counts(const int* __restrict__ adj, int* __restrict__ counts, int E) {
  int e = blockIdx.x * 256 + threadIdx.x;
  if (e >= E) return;
  int t = blockIdx.y, t4 = t & 3;
  int a = adj[(size_t)(t4 * E + e) * 2], b = adj[(size_t)(t4 * E + e) * 2 + 1];
  int dst = (t < 4) ? b : a;
  atomicAdd(&counts[dst], 1);
}

__global__ __launch_bounds__(1024) void k_scan(const int* __restrict__ counts,
                                               int* __restrict__ offsets, int n) {
  __shared__ int part[1024];
  int tid = threadIdx.x;
  int chunk = (((n + 1023) >> 10) + 3) & ~3;
  int begin = tid * chunk;
  int end = min(begin + chunk, n);
  int s = 0;
  int i = begin;
  for (; i + 4 <= end; i += 4) {
    int4 v = *(const int4*)&counts[i];
    s += v.x + v.y + v.z + v.w;
  }
  for (; i < end; ++i) s += counts[i];
  part[tid] = s;
  __syncthreads();
  for (int off = 1; off < 1024; off <<= 1) {
    int v = (tid >= off) ? part[tid - off] : 0;
    __syncthreads();
    part[tid] += v;
    __syncthreads();
  }
  int run = part[tid] - s;
  i = begin;
  for (; i + 4 <= end; i += 4) {
    int4 c = *(const int4*)&counts[i];
    int4 o;
    o.x = run; o.y = run + c.x; o.z = o.y + c.y; o.w = o.z + c.z;
    *(int4*)&offsets[i] = o;
    run = o.w + c.w;
  }
  for (; i < end; ++i) { offsets[i] = run; run += counts[i]; }
  if (tid == 1023) offsets[n] = part[1023];
}

// group0 (t<4) fills from front via curA; group1 from back via curB.
// group1 entries stored with type already rebased (t-4).
__global__ void k_fill(const int* __restrict__ adj, int* __restrict__ curA,
                       int* __restrict__ curB, int* __restrict__ entries,
                       int E, int N) {
  int e = blockIdx.x * 256 + threadIdx.x;
  if (e >= E) return;
  int t = blockIdx.y, t4 = t & 3;
  int a = adj[(size_t)(t4 * E + e) * 2], b = adj[(size_t)(t4 * E + e) * 2 + 1];
  int src = (t < 4) ? a : b;
  int dst = (t < 4) ? b : a;
  if (t < 4) {
    int pos = atomicAdd(&curA[dst], 1);
    entries[pos] = t * N + src;
  } else {
    int pos = atomicSub(&curB[dst], 1) - 1;
    entries[pos] = (t - 4) * N + src;
  }
}

// ---------- unified split-bf16 MFMA GEMM ----------
// C[m][jt+j] (+bias) = sum_k A[m][k] * W[k][jt+j]; A = (A0h+A0l) [, A1 for k>=64]
// block: 256 thr = 4 waves, tile 128 rows; wave w -> rows w*32..w*32+31.
// typeMode: blockIdx.y = edge type slot (W += (typeBase+y)*8192, C += y*N*64)
// else:     blockIdx.y = 64-col group (ctBase = y*4, jt = y*64)
__global__ __launch_bounds__(256) void k_mm(
    const unsigned short* __restrict__ A0h, const unsigned short* __restrict__ A0l,
    const unsigned short* A1h, const unsigned short* A1l,
    const unsigned short* __restrict__ Wf, const float* bias,
    float* __restrict__ C, int ldc, int N, int nct, int typeMode, int typeBase) {
  int tid = threadIdx.x;
  int wv = tid >> 6, lane = tid & 63;
  int lr = lane & 15, lg = lane >> 4;
  int y = blockIdx.y;
  const unsigned short* Wfb;
  float* Cb;
  int ctBase, jt;
  int nkc = A1h ? 4 : 2;
  if (typeMode) {
    Wfb = Wf + (size_t)(typeBase + y) * 8192;
    Cb = C + (size_t)y * N * 64;
    ctBase = 0; jt = 0;
  } else {
    Wfb = Wf; Cb = C; ctBase = y * 4; jt = y * 64;
  }
  int m0 = blockIdx.x * 128 + wv * 32;
  v4f acc[2][4] = {};
  for (int kc = 0; kc < nkc; ++kc) {
    const unsigned short* Ah = (kc < 2) ? A0h : A1h;
    const unsigned short* Al = (kc < 2) ? A0l : A1l;
    int kcl = kc & 1;
    v8s ah[2], al[2];
#pragma unroll
    for (int mt = 0; mt < 2; ++mt) {
      int row = min(m0 + mt * 16 + lr, N - 1);
      size_t off = (size_t)row * 64 + kcl * 32 + lg * 8;
      ah[mt] = *(const v8s*)&Ah[off];
      al[mt] = *(const v8s*)&Al[off];
    }
#pragma unroll
    for (int ct = 0; ct < 4; ++ct) {
      int cta = ctBase + ct;
      v8s bh = *(const v8s*)&Wfb[((size_t)(0 * nkc + kc) * nct + cta) * 512 + lane * 8];
      v8s bl = *(const v8s*)&Wfb[((size_t)(nkc + kc) * nct + cta) * 512 + lane * 8];
#pragma unroll
      for (int mt = 0; mt < 2; ++mt) {
        acc[mt][ct] = __builtin_amdgcn_mfma_f32_16x16x32_bf16(ah[mt], bh, acc[mt][ct], 0, 0, 0);
        acc[mt][ct] = __builtin_amdgcn_mfma_f32_16x16x32_bf16(al[mt], bh, acc[mt][ct], 0, 0, 0);
        acc[mt][ct] = __builtin_amdgcn_mfma_f32_16x16x32_bf16(ah[mt], bl, acc[mt][ct], 0, 0, 0);
      }
    }
  }
#pragma unroll
  for (int ct = 0; ct < 4; ++ct) {
    float bv = bias ? bias[jt + ct * 16 + lr] : 0.f;
#pragma unroll
    for (int mt = 0; mt < 2; ++mt)
#pragma unroll
      for (int r = 0; r < 4; ++r) {
        int m = m0 + mt * 16 + lg * 4 + r;
        if (m < N) Cb[(size_t)m * ldc + jt + ct * 16 + lr] = acc[mt][ct][r] + bv;
      }
  }
}

// ---------- segment-max over CSR (two passes, branch-free ranges) ----------
__global__ __launch_bounds__(256) void k_aggmax(
    const float* __restrict__ Ht, const int* __restrict__ offsets,
    const int* __restrict__ splits, float* __restrict__ msgtmp,
    unsigned short* __restrict__ mh, unsigned short* __restrict__ ml,
    int N, int pass) {
  int w = threadIdx.x >> 6, lane = threadIdx.x & 63;
  int n = blockIdx.x * 4 + w;
  if (n >= N) return;
  int beg, end;
  float m;
  const int* entries = splits + N + 64;  // entries stored after splits (see carve)
  if (pass == 0) {
    beg = offsets[n]; end = splits[n];
    m = -3.4e38f;
  } else {
    beg = splits[n]; end = offsets[n + 1];
    m = msgtmp[(size_t)n * 64 + lane];
  }
  int i = beg;
  float m2 = -3.4e38f;
  for (; i + 4 <= end; i += 4) {
    int e0 = entries[i], e1 = entries[i + 1], e2 = entries[i + 2], e3 = entries[i + 3];
    float v0 = Ht[(size_t)e0 * 64 + lane];
    float v1 = Ht[(size_t)e1 * 64 + lane];
    float v2 = Ht[(size_t)e2 * 64 + lane];
    float v3 = Ht[(size_t)e3 * 64 + lane];
    m = fmaxf(m, fmaxf(v0, v1));
    m2 = fmaxf(m2, fmaxf(v2, v3));
  }
  m = fmaxf(m, m2);
  for (; i < end; ++i) m = fmaxf(m, Ht[(size_t)entries[i] * 64 + lane]);
  if (pass == 0) {
    msgtmp[(size_t)n * 64 + lane] = m;
  } else {
    float v = (m > -1e37f) ? m : 0.f;
    unsigned short h = f2bf(v);
    mh[(size_t)n * 64 + lane] = h;
    ml[(size_t)n * 64 + lane] = f2bf(v - bf2f(h));
  }
}

// ---------- fused h@Wh MFMA + GRU gate epilogue ----------
// gh = (hh+hl)@Wh; gates from gx [N,192]; out f32 and/or bf16 pair (in-place ok).
__global__ __launch_bounds__(256) void k_gruh(
    const unsigned short* hh, const unsigned short* hl,
    const float* __restrict__ gx, const unsigned short* __restrict__ Whf,
    float* outF, unsigned short* oh, unsigned short* ol, int N) {
  int tid = threadIdx.x;
  int wv = tid >> 6, lane = tid & 63;
  int lr = lane & 15, lg = lane >> 4;
  int m0 = blockIdx.x * 128 + wv * 32;
  v4f acc[2][12] = {};
#pragma unroll
  for (int kc = 0; kc < 2; ++kc) {
    v8s ah[2], al[2];
#pragma unroll
    for (int mt = 0; mt < 2; ++mt) {
      int row = min(m0 + mt * 16 + lr, N - 1);
      size_t off = (size_t)row * 64 + kc * 32 + lg * 8;
      ah[mt] = *(const v8s*)&hh[off];
      al[mt] = *(const v8s*)&hl[off];
    }
#pragma unroll
    for (int ct = 0; ct < 12; ++ct) {
      v8s bh = *(const v8s*)&Whf[((size_t)(0 * 2 + kc) * 12 + ct) * 512 + lane * 8];
      v8s bl = *(const v8s*)&Whf[((size_t)(2 + kc) * 12 + ct) * 512 + lane * 8];
#pragma unroll
      for (int mt = 0; mt < 2; ++mt) {
        acc[mt][ct] = __builtin_amdgcn_mfma_f32_16x16x32_bf16(ah[mt], bh, acc[mt][ct], 0, 0, 0);
        acc[mt][ct] = __builtin_amdgcn_mfma_f32_16x16x32_bf16(al[mt], bh, acc[mt][ct], 0, 0, 0);
        acc[mt][ct] = __builtin_amdgcn_mfma_f32_16x16x32_bf16(ah[mt], bl, acc[mt][ct], 0, 0, 0);
      }
    }
  }
#pragma unroll
  for (int mt = 0; mt < 2; ++mt)
#pragma unroll
    for (int ctg = 0; ctg < 4; ++ctg)
#pragma unroll
      for (int r = 0; r < 4; ++r) {
        int m = m0 + mt * 16 + lg * 4 + r;
        if (m >= N) continue;
        int col = ctg * 16 + lr;
        float gr = gx[(size_t)m * 192 + col];
        float gu = gx[(size_t)m * 192 + 64 + col];
        float gc = gx[(size_t)m * 192 + 128 + col];
        float hv = bf2f(hh[(size_t)m * 64 + col]) + bf2f(hl[(size_t)m * 64 + col]);
        float rr = sigmoidf_(gr + acc[mt][ctg][r]);
        float uu = sigmoidf_(gu + acc[mt][ctg + 4][r]);
        float cc = tanhf_(gc + rr * acc[mt][ctg + 8][r]);
        float ho = uu * hv + (1.f - uu) * cc;
        if (outF) outF[(size_t)m * 64 + col] = ho;
        if (oh) {
          unsigned short hb = f2bf(ho);
          oh[(size_t)m * 64 + col] = hb;
          ol[(size_t)m * 64 + col] = f2bf(ho - bf2f(hb));
        }
      }
}

extern "C" void kernel_launch(void* const* d_in, const int* in_sizes, int n_in,
                              void* d_out, int out_size, void* d_ws, size_t ws_size,
                              hipStream_t stream) {
  const int*   toks  = (const int*)d_in[0];
  const int*   adj   = (const int*)d_in[1];
  const float* embed = (const float*)d_in[2];
  const float* projW = (const float*)d_in[3];
  const float* eW0   = (const float*)d_in[4];
  const float* eW1   = (const float*)d_in[5];
  const float* g0Wx  = (const float*)d_in[6];
  const float* g0Wh  = (const float*)d_in[7];
  const float* g0b   = (const float*)d_in[8];
  const float* g1Wx  = (const float*)d_in[9];
  const float* g1Wh  = (const float*)d_in[10];
  const float* g1b   = (const float*)d_in[11];
  float* out = (float*)d_out;

  int N = in_sizes[0] / 5;
  int E = in_sizes[1] / 8;
  size_t ND = (size_t)N * 64;

  char* p = (char*)d_ws;
  float* Ht     = (float*)p; p += 4 * ND * sizeof(float);          // 61.4MB (+aliases)
  float* msgtmp = (float*)p; p += ND * sizeof(float);              // 15.4MB
  unsigned short* h_hi  = (unsigned short*)p; p += ND * 2;
  unsigned short* h_lo  = (unsigned short*)p; p += ND * 2;
  unsigned short* hi_hi = (unsigned short*)p; p += ND * 2;
  unsigned short* hi_lo = (unsigned short*)p; p += ND * 2;
  unsigned short* m_hi  = (unsigned short*)p; p += ND * 2;
  unsigned short* m_lo  = (unsigned short*)p; p += ND * 2;
  int* offsets = (int*)p; p += (size_t)(N + 64) * sizeof(int);
  int* splits  = (int*)p; p += (size_t)(N + 64) * sizeof(int);     // curA; entries follow
  int* entries = (int*)p; p += (size_t)8 * E * sizeof(int);        // MUST follow splits+N+64
  int* curB    = (int*)p; p += (size_t)(N + 64) * sizeof(int);
  int* counts  = (int*)p; p += (size_t)(N + 64) * sizeof(int);
  unsigned short* eW0f  = (unsigned short*)p; p += 65536 * 2;
  unsigned short* eW1f  = (unsigned short*)p; p += 65536 * 2;
  unsigned short* projf = (unsigned short*)p; p += 8192 * 2;
  unsigned short* g0xf  = (unsigned short*)p; p += 24576 * 2;
  unsigned short* g0hf  = (unsigned short*)p; p += 24576 * 2;
  unsigned short* g1xf  = (unsigned short*)p; p += 49152 * 2;
  unsigned short* g1hf  = (unsigned short*)p; p += 24576 * 2;
  if ((size_t)(p - (char*)d_ws) > ws_size) return;

  // init-phase aliases inside Ht region
  unsigned short* emb_h = (unsigned short*)Ht;
  unsigned short* emb_l = emb_h + ND;
  float* h_init_tmp = (float*)((char*)Ht + ((ND * 4 + 255) & ~(size_t)255));
  float* gbuf = Ht;  // [N,192] f32, used after Ht consumed each iter

  int g128 = (N + 127) / 128;
  int g4 = (N + 3) / 4;

  // ---- weight prep ----
  k_wprep<<<(8 * 8192 + 255) / 256, 256, 0, stream>>>(eW0, eW0f, 64, 64, 8 * 8192);
  k_wprep<<<(8 * 8192 + 255) / 256, 256, 0, stream>>>(eW1, eW1f, 64, 64, 8 * 8192);
  k_wprep<<<(8192 + 255) / 256, 256, 0, stream>>>(projW, projf, 64, 64, 8192);
  k_wprep<<<(24576 + 255) / 256, 256, 0, stream>>>(g0Wx, g0xf, 64, 192, 24576);
  k_wprep<<<(24576 + 255) / 256, 256, 0, stream>>>(g0Wh, g0hf, 64, 192, 24576);
  k_wprep<<<(49152 + 255) / 256, 256, 0, stream>>>(g1Wx, g1xf, 128, 192, 49152);
  k_wprep<<<(24576 + 255) / 256, 256, 0, stream>>>(g1Wh, g1hf, 64, 192, 24576);

  // ---- h_init = (mean embed) @ projW; split to pairs ----
  k_embed<<<g4, 256, 0, stream>>>(toks, embed, emb_h, emb_l, N);
  k_mm<<<dim3(g128, 1), 256, 0, stream>>>(emb_h, emb_l, nullptr, nullptr, projf,
                                          nullptr, h_init_tmp, 64, N, 4, 0, 0);
  k_split<<<((int)(ND / 4) + 255) / 256, 256, 0, stream>>>(
      h_init_tmp, hi_hi, hi_lo, h_hi, h_lo, (int)ND);

  // ---- CSR ----
  hipMemsetAsync(counts, 0, (size_t)N * sizeof(int), stream);
  dim3 egrid((E + 255) / 256, 8);
  k_counts<<<egrid, 256, 0, stream>>>(adj, counts, E);
  k_scan<<<1, 1024, 0, stream>>>(counts, offsets, N);
  hipMemcpyAsync(splits, offsets, (size_t)N * sizeof(int),
                 hipMemcpyDeviceToDevice, stream);
  hipMemcpyAsync(curB, offsets + 1, (size_t)N * sizeof(int),
                 hipMemcpyDeviceToDevice, stream);
  k_fill<<<egrid, 256, 0, stream>>>(adj, splits, curB, entries, E, N);

  // ---- propagation ----
  for (int it = 0; it < 8; ++it) {
    const unsigned short* ef = (it < 7) ? eW0f : eW1f;
    k_mm<<<dim3(g128, 4), 256, 0, stream>>>(h_hi, h_lo, nullptr, nullptr, ef,
                                            nullptr, Ht, 64, N, 4, 1, 0);
    k_aggmax<<<g4, 256, 0, stream>>>(Ht, offsets, splits, msgtmp, m_hi, m_lo, N, 0);
    k_mm<<<dim3(g128, 4), 256, 0, stream>>>(h_hi, h_lo, nullptr, nullptr, ef,
                                            nullptr, Ht, 64, N, 4, 1, 4);
    k_aggmax<<<g4, 256, 0, stream>>>(Ht, offsets, splits, msgtmp, m_hi, m_lo, N, 1);
    if (it < 7) {
      k_mm<<<dim3(g128, 3), 256, 0, stream>>>(m_hi, m_lo, nullptr, nullptr, g0xf,
                                              g0b, gbuf, 192, N, 12, 0, 0);
      k_gruh<<<g128, 256, 0, stream>>>(h_hi, h_lo, gbuf, g0hf,
                                       nullptr, h_hi, h_lo, N);
    } else {
      k_mm<<<dim3(g128, 3), 256, 0, stream>>>(hi_hi, hi_lo, m_hi, m_lo, g1xf,
                                              g1b, gbuf, 192, N, 12, 0, 0);
      k_gruh<<<g128, 256, 0, stream>>>(h_hi, h_lo, gbuf, g1hf,
                                       out, nullptr, nullptr, N);
    }
  }
}

// Round 4
// 1339.986 us; speedup vs baseline: 9.7889x; 1.1769x over previous
//
#include <hip/hip_runtime.h>

typedef short v8s __attribute__((ext_vector_type(8)));
typedef float v4f __attribute__((ext_vector_type(4)));

__device__ __forceinline__ unsigned short f2bf(float x) {
  unsigned u = __float_as_uint(x);
  u = u + 0x7FFFu + ((u >> 16) & 1u);
  return (unsigned short)(u >> 16);
}
__device__ __forceinline__ float bf2f(unsigned short b) {
  return __uint_as_float(((unsigned)b) << 16);
}
__device__ __forceinline__ float sigmoidf_(float x) {
  return 1.f / (1.f + __expf(-x));
}
__device__ __forceinline__ float tanhf_(float x) {
  x = fminf(fmaxf(x, -20.f), 20.f);
  float e2 = __expf(2.f * x);
  return (e2 - 1.f) / (e2 + 1.f);
}

// ---------- embedding gather -> bf16 hi/lo planes ----------
__global__ __launch_bounds__(256) void k_embed(
    const int* __restrict__ toks, const float* __restrict__ embed,
    unsigned short* __restrict__ eh, unsigned short* __restrict__ el, int N) {
  int w = threadIdx.x >> 6, lane = threadIdx.x & 63;
  int n = blockIdx.x * 4 + w;
  if (n >= N) return;
  float acc = 0.f;
#pragma unroll
  for (int s = 0; s < 5; ++s)
    acc += embed[(size_t)toks[n * 5 + s] * 64 + lane];
  float v = acc * 0.2f;
  unsigned short h = f2bf(v);
  eh[(size_t)n * 64 + lane] = h;
  el[(size_t)n * 64 + lane] = f2bf(v - bf2f(h));
}

// ---------- merged weight prep ----------
// frag layout per weight: idx = ((p*nkc + kc)*nct + ct)*512 + lane*8 + j
// value: W[t][kc*32+(lane>>4)*8+j][ct*16+(lane&15)], p=0 hi, p=1 lo.
__device__ __forceinline__ void wprep_one(const float* W, unsigned short* O,
                                          int K, int J, int idx) {
  int nkc = K >> 5, nct = J >> 4;
  int j = idx & 7, lane = (idx >> 3) & 63;
  int rest = idx >> 9;
  int ct = rest % nct; rest /= nct;
  int kc = rest % nkc; rest /= nkc;
  int p = rest & 1, t = rest >> 1;
  int row = kc * 32 + (lane >> 4) * 8 + j;
  int col = ct * 16 + (lane & 15);
  float v = W[(size_t)t * K * J + (size_t)row * J + col];
  unsigned short hi = f2bf(v);
  O[idx] = p ? f2bf(v - bf2f(hi)) : hi;
}

__global__ void k_wprep_all(
    const float* eW0, const float* eW1, const float* projW,
    const float* g0Wx, const float* g0Wh, const float* g1Wx, const float* g1Wh,
    unsigned short* eW0f, unsigned short* eW1f, unsigned short* projf,
    unsigned short* g0xf, unsigned short* g0hf,
    unsigned short* g1xf, unsigned short* g1hf) {
  int rel = blockIdx.x * 256 + threadIdx.x;
  if (rel < 65536) { wprep_one(eW0, eW0f, 64, 64, rel); return; }
  rel -= 65536;
  if (rel < 65536) { wprep_one(eW1, eW1f, 64, 64, rel); return; }
  rel -= 65536;
  if (rel < 8192)  { wprep_one(projW, projf, 64, 64, rel); return; }
  rel -= 8192;
  if (rel < 24576) { wprep_one(g0Wx, g0xf, 64, 192, rel); return; }
  rel -= 24576;
  if (rel < 24576) { wprep_one(g0Wh, g0hf, 64, 192, rel); return; }
  rel -= 24576;
  if (rel < 49152) { wprep_one(g1Wx, g1xf, 128, 192, rel); return; }
  rel -= 49152;
  if (rel < 24576) { wprep_one(g1Wh, g1hf, 64, 192, rel); return; }
}

// ---------- f32 -> hi/lo pair + single-bf16 copy ----------
__global__ void k_split3(const float* __restrict__ src,
                         unsigned short* __restrict__ hh, unsigned short* __restrict__ hl,
                         unsigned short* __restrict__ hb, int total) {
  int i = (blockIdx.x * 256 + threadIdx.x) * 4;
  if (i >= total) return;
  float4 v = *(const float4*)&src[i];
  ushort4 H, L;
  H.x = f2bf(v.x); L.x = f2bf(v.x - bf2f(H.x));
  H.y = f2bf(v.y); L.y = f2bf(v.y - bf2f(H.y));
  H.z = f2bf(v.z); L.z = f2bf(v.z - bf2f(H.z));
  H.w = f2bf(v.w); L.w = f2bf(v.w - bf2f(H.w));
  *(ushort4*)&hh[i] = H; *(ushort4*)&hl[i] = L; *(ushort4*)&hb[i] = H;
}

// ---------- CSR build ----------
__global__ void k_counts(const int* __restrict__ adj, int* __restrict__ counts, int E) {
  int e = blockIdx.x * 256 + threadIdx.x;
  if (e >= E) return;
  int t = blockIdx.y, t4 = t & 3;
  int a = adj[(size_t)(t4 * E + e) * 2], b = adj[(size_t)(t4 * E + e) * 2 + 1];
  int dst = (t < 4) ? b : a;
  atomicAdd(&counts[dst], 1);
}

__global__ __launch_bounds__(1024) void k_scan(const int* __restrict__ counts,
                                               int* __restrict__ offsets, int n) {
  __shared__ int part[1024];
  int tid = threadIdx.x;
  int chunk = (((n + 1023) >> 10) + 3) & ~3;
  int begin = tid * chunk;
  int end = min(begin + chunk, n);
  int s = 0;
  int i = begin;
  for (; i + 4 <= end; i += 4) {
    int4 v = *(const int4*)&counts[i];
    s += v.x + v.y + v.z + v.w;
  }
  for (; i < end; ++i) s += counts[i];
  part[tid] = s;
  __syncthreads();
  for (int off = 1; off < 1024; off <<= 1) {
    int v = (tid >= off) ? part[tid - off] : 0;
    __syncthreads();
    part[tid] += v;
    __syncthreads();
  }
  int run = part[tid] - s;
  i = begin;
  for (; i + 4 <= end; i += 4) {
    int4 c = *(const int4*)&counts[i];
    int4 o;
    o.x = run; o.y = run + c.x; o.z = o.y + c.y; o.w = o.z + c.z;
    *(int4*)&offsets[i] = o;
    run = o.w + c.w;
  }
  for (; i < end; ++i) { offsets[i] = run; run += counts[i]; }
  if (tid == 1023) offsets[n] = part[1023];
}

__global__ void k_fill(const int* __restrict__ adj, int* __restrict__ cursor,
                       int* __restrict__ entries, int E, int N) {
  int e = blockIdx.x * 256 + threadIdx.x;
  if (e >= E) return;
  int t = blockIdx.y, t4 = t & 3;
  int a = adj[(size_t)(t4 * E + e) * 2], b = adj[(size_t)(t4 * E + e) * 2 + 1];
  int src = (t < 4) ? a : b;
  int dst = (t < 4) ? b : a;
  int pos = atomicAdd(&cursor[dst], 1);
  entries[pos] = t * N + src;
}

// ---------- split-bf16 MFMA GEMM (proj + 8-type transform) ----------
__global__ __launch_bounds__(256) void k_mm(
    const unsigned short* __restrict__ A0h, const unsigned short* __restrict__ A0l,
    const unsigned short* __restrict__ Wf, float* __restrict__ C,
    int N, int typeMode) {
  int tid = threadIdx.x;
  int wv = tid >> 6, lane = tid & 63;
  int lr = lane & 15, lg = lane >> 4;
  const unsigned short* Wfb = Wf;
  float* Cb = C;
  if (typeMode) {
    Wfb = Wf + (size_t)blockIdx.y * 8192;
    Cb = C + (size_t)blockIdx.y * N * 64;
  }
  int m0 = blockIdx.x * 128 + wv * 32;
  v4f acc[2][4] = {};
#pragma unroll
  for (int kc = 0; kc < 2; ++kc) {
    v8s ah[2], al[2];
#pragma unroll
    for (int mt = 0; mt < 2; ++mt) {
      int row = min(m0 + mt * 16 + lr, N - 1);
      size_t off = (size_t)row * 64 + kc * 32 + lg * 8;
      ah[mt] = *(const v8s*)&A0h[off];
      al[mt] = *(const v8s*)&A0l[off];
    }
#pragma unroll
    for (int ct = 0; ct < 4; ++ct) {
      v8s bh = *(const v8s*)&Wfb[((size_t)(kc * 4 + ct)) * 512 + lane * 8];
      v8s bl = *(const v8s*)&Wfb[((size_t)((2 + kc) * 4 + ct)) * 512 + lane * 8];
#pragma unroll
      for (int mt = 0; mt < 2; ++mt) {
        acc[mt][ct] = __builtin_amdgcn_mfma_f32_16x16x32_bf16(ah[mt], bh, acc[mt][ct], 0, 0, 0);
        acc[mt][ct] = __builtin_amdgcn_mfma_f32_16x16x32_bf16(al[mt], bh, acc[mt][ct], 0, 0, 0);
        acc[mt][ct] = __builtin_amdgcn_mfma_f32_16x16x32_bf16(ah[mt], bl, acc[mt][ct], 0, 0, 0);
      }
    }
  }
#pragma unroll
  for (int ct = 0; ct < 4; ++ct)
#pragma unroll
    for (int mt = 0; mt < 2; ++mt)
#pragma unroll
      for (int r = 0; r < 4; ++r) {
        int m = m0 + mt * 16 + lg * 4 + r;
        if (m < N) Cb[(size_t)m * 64 + ct * 16 + lr] = acc[mt][ct][r];
      }
}

// ---------- segment-max over CSR (single pass) ----------
__global__ __launch_bounds__(256) void k_aggmax(
    const float* __restrict__ Ht, const int* __restrict__ offsets,
    const int* __restrict__ entries,
    unsigned short* __restrict__ mh, unsigned short* __restrict__ ml, int N) {
  int w = threadIdx.x >> 6, lane = threadIdx.x & 63;
  int n = blockIdx.x * 4 + w;
  if (n >= N) return;
  int beg = offsets[n], end = offsets[n + 1];
  float m = -3.4e38f, m2 = -3.4e38f;
  int i = beg;
  for (; i + 4 <= end; i += 4) {
    int e0 = entries[i], e1 = entries[i + 1], e2 = entries[i + 2], e3 = entries[i + 3];
    float v0 = Ht[(size_t)e0 * 64 + lane];
    float v1 = Ht[(size_t)e1 * 64 + lane];
    float v2 = Ht[(size_t)e2 * 64 + lane];
    float v3 = Ht[(size_t)e3 * 64 + lane];
    m = fmaxf(m, fmaxf(v0, v1));
    m2 = fmaxf(m2, fmaxf(v2, v3));
  }
  m = fmaxf(m, m2);
  for (; i < end; ++i) m = fmaxf(m, Ht[(size_t)entries[i] * 64 + lane]);
  float v = (end > beg) ? m : 0.f;
  unsigned short h = f2bf(v);
  mh[(size_t)n * 64 + lane] = h;
  ml[(size_t)n * 64 + lane] = f2bf(v - bf2f(h));
}

// ---------- fused GRU ----------
// gates: r = sig(xr+hr), u = sig(xu+hu), c = tanh(xc + r*hc)  ->  the c-gate's
// h-part needs its own accumulators (r multiplies hc only): acc x-side 12 ct,
// acc h-side r/u merged into x acc, hc separate 4 ct. Total acc = 16 v4f per mt.
// NKCX=2: x = (x0h+x0l). NKCX=4: x = concat(x0h single-bf16, x1h+x1l).
template <int NKCX>
__global__ __launch_bounds__(256) void k_gru(
    const unsigned short* __restrict__ x0h, const unsigned short* __restrict__ x0l,
    const unsigned short* __restrict__ x1h, const unsigned short* __restrict__ x1l,
    const unsigned short* __restrict__ hh, const unsigned short* __restrict__ hl,
    const unsigned short* __restrict__ Wxf, const unsigned short* __restrict__ Whf,
    const float* __restrict__ bias,
    float* outF, unsigned short* oh, unsigned short* ol, int N) {
  int tid = threadIdx.x;
  int wv = tid >> 6, lane = tid & 63;
  int lr = lane & 15, lg = lane >> 4;
  int m0 = blockIdx.x * 128 + wv * 32;
  v4f acc[2][12] = {};   // xr,xu,xc (+hr,hu merged)
  v4f acch[2][4] = {};   // hc separate
  // x @ Wx -> all 12 col-tiles
#pragma unroll
  for (int kc = 0; kc < NKCX; ++kc) {
    const bool fromX1 = (NKCX == 4) && (kc >= 2);
    const bool hasL = (NKCX == 2) || fromX1;
    const unsigned short* Xh = fromX1 ? x1h : x0h;
    const unsigned short* Xl = fromX1 ? x1l : x0l;
    int kcl = kc & 1;
    v8s ah[2], al[2];
#pragma unroll
    for (int mt = 0; mt < 2; ++mt) {
      int row = min(m0 + mt * 16 + lr, N - 1);
      size_t off = (size_t)row * 64 + kcl * 32 + lg * 8;
      ah[mt] = *(const v8s*)&Xh[off];
      al[mt] = hasL ? *(const v8s*)&Xl[off] : v8s{0, 0, 0, 0, 0, 0, 0, 0};
    }
#pragma unroll
    for (int ct = 0; ct < 12; ++ct) {
      v8s bh = *(const v8s*)&Wxf[((size_t)(kc * 12 + ct)) * 512 + lane * 8];
      v8s bl = *(const v8s*)&Wxf[((size_t)((NKCX + kc) * 12 + ct)) * 512 + lane * 8];
#pragma unroll
      for (int mt = 0; mt < 2; ++mt) {
        acc[mt][ct] = __builtin_amdgcn_mfma_f32_16x16x32_bf16(ah[mt], bh, acc[mt][ct], 0, 0, 0);
        if (hasL)
          acc[mt][ct] = __builtin_amdgcn_mfma_f32_16x16x32_bf16(al[mt], bh, acc[mt][ct], 0, 0, 0);
        acc[mt][ct] = __builtin_amdgcn_mfma_f32_16x16x32_bf16(ah[mt], bl, acc[mt][ct], 0, 0, 0);
      }
    }
  }
  // h @ Wh: r,u tiles (ct 0..7) merge into acc; c tiles (ct 8..11) -> acch
#pragma unroll
  for (int kc = 0; kc < 2; ++kc) {
    v8s ah[2], al[2];
#pragma unroll
    for (int mt = 0; mt < 2; ++mt) {
      int row = min(m0 + mt * 16 + lr, N - 1);
      size_t off = (size_t)row * 64 + kc * 32 + lg * 8;
      ah[mt] = *(const v8s*)&hh[off];
      al[mt] = *(const v8s*)&hl[off];
    }
#pragma unroll
    for (int ct = 0; ct < 12; ++ct) {
      v8s bh = *(const v8s*)&Whf[((size_t)(kc * 12 + ct)) * 512 + lane * 8];
      v8s bl = *(const v8s*)&Whf[((size_t)((2 + kc) * 12 + ct)) * 512 + lane * 8];
#pragma unroll
      for (int mt = 0; mt < 2; ++mt) {
        v4f* d = (ct < 8) ? &acc[mt][ct] : &acch[mt][ct - 8];
        *d = __builtin_amdgcn_mfma_f32_16x16x32_bf16(ah[mt], bh, *d, 0, 0, 0);
        *d = __builtin_amdgcn_mfma_f32_16x16x32_bf16(al[mt], bh, *d, 0, 0, 0);
        *d = __builtin_amdgcn_mfma_f32_16x16x32_bf16(ah[mt], bl, *d, 0, 0, 0);
      }
    }
  }
  // gate epilogue
#pragma unroll
  for (int mt = 0; mt < 2; ++mt)
#pragma unroll
    for (int ctg = 0; ctg < 4; ++ctg)
#pragma unroll
      for (int r = 0; r < 4; ++r) {
        int m = m0 + mt * 16 + lg * 4 + r;
        if (m >= N) continue;
        int col = ctg * 16 + lr;
        float hv = bf2f(hh[(size_t)m * 64 + col]) + bf2f(hl[(size_t)m * 64 + col]);
        float rr = sigmoidf_(acc[mt][ctg][r] + bias[col]);
        float uu = sigmoidf_(acc[mt][ctg + 4][r] + bias[64 + col]);
        float cc = tanhf_(acc[mt][ctg + 8][r] + bias[128 + col] + rr * acch[mt][ctg][r]);
        float ho = uu * hv + (1.f - uu) * cc;
        if (outF) outF[(size_t)m * 64 + col] = ho;
        if (oh) {
          unsigned short hb = f2bf(ho);
          oh[(size_t)m * 64 + col] = hb;
          ol[(size_t)m * 64 + col] = f2bf(ho - bf2f(hb));
        }
      }
}

extern "C" void kernel_launch(void* const* d_in, const int* in_sizes, int n_in,
                              void* d_out, int out_size, void* d_ws, size_t ws_size,
                              hipStream_t stream) {
  const int*   toks  = (const int*)d_in[0];
  const int*   adj   = (const int*)d_in[1];
  const float* embed = (const float*)d_in[2];
  const float* projW = (const float*)d_in[3];
  const float* eW0   = (const float*)d_in[4];
  const float* eW1   = (const float*)d_in[5];
  const float* g0Wx  = (const float*)d_in[6];
  const float* g0Wh  = (const float*)d_in[7];
  const float* g0b   = (const float*)d_in[8];
  const float* g1Wx  = (const float*)d_in[9];
  const float* g1Wh  = (const float*)d_in[10];
  const float* g1b   = (const float*)d_in[11];
  float* out = (float*)d_out;

  int N = in_sizes[0] / 5;
  int E = in_sizes[1] / 8;
  size_t ND = (size_t)N * 64;

  char* p = (char*)d_ws;
  float* Ht = (float*)p; p += 8 * ND * sizeof(float);              // 122.9 MB
  unsigned short* h_hi    = (unsigned short*)p; p += ND * 2;
  unsigned short* h_lo    = (unsigned short*)p; p += ND * 2;
  unsigned short* hinit_b = (unsigned short*)p; p += ND * 2;
  unsigned short* m_hi    = (unsigned short*)p; p += ND * 2;
  unsigned short* m_lo    = (unsigned short*)p; p += ND * 2;
  int* offsets = (int*)p; p += (size_t)(N + 64) * sizeof(int);
  int* cnt_cur = (int*)p; p += (size_t)(N + 64) * sizeof(int);     // counts then cursor
  int* entries = (int*)p; p += (size_t)8 * E * sizeof(int);
  unsigned short* eW0f  = (unsigned short*)p; p += 65536 * 2;
  unsigned short* eW1f  = (unsigned short*)p; p += 65536 * 2;
  unsigned short* projf = (unsigned short*)p; p += 8192 * 2;
  unsigned short* g0xf  = (unsigned short*)p; p += 24576 * 2;
  unsigned short* g0hf  = (unsigned short*)p; p += 24576 * 2;
  unsigned short* g1xf  = (unsigned short*)p; p += 49152 * 2;
  unsigned short* g1hf  = (unsigned short*)p; p += 24576 * 2;
  if ((size_t)(p - (char*)d_ws) > ws_size) return;

  // init-phase aliases inside Ht
  unsigned short* emb_h = (unsigned short*)Ht;
  unsigned short* emb_l = emb_h + ND;
  float* h_init_tmp = (float*)(emb_h + 2 * ND);

  int g128 = (N + 127) / 128;
  int g4 = (N + 3) / 4;

  k_wprep_all<<<1024, 256, 0, stream>>>(eW0, eW1, projW, g0Wx, g0Wh, g1Wx, g1Wh,
                                        eW0f, eW1f, projf, g0xf, g0hf, g1xf, g1hf);
  k_embed<<<g4, 256, 0, stream>>>(toks, embed, emb_h, emb_l, N);
  k_mm<<<dim3(g128, 1), 256, 0, stream>>>(emb_h, emb_l, projf, h_init_tmp, N, 0);
  k_split3<<<((int)(ND / 4) + 255) / 256, 256, 0, stream>>>(
      h_init_tmp, h_hi, h_lo, hinit_b, (int)ND);

  hipMemsetAsync(cnt_cur, 0, (size_t)N * sizeof(int), stream);
  dim3 egrid((E + 255) / 256, 8);
  k_counts<<<egrid, 256, 0, stream>>>(adj, cnt_cur, E);
  k_scan<<<1, 1024, 0, stream>>>(cnt_cur, offsets, N);
  hipMemcpyAsync(cnt_cur, offsets, (size_t)N * sizeof(int),
                 hipMemcpyDeviceToDevice, stream);
  k_fill<<<egrid, 256, 0, stream>>>(adj, cnt_cur, entries, E, N);

  for (int it = 0; it < 8; ++it) {
    const unsigned short* ef = (it < 7) ? eW0f : eW1f;
    k_mm<<<dim3(g128, 8), 256, 0, stream>>>(h_hi, h_lo, ef, Ht, N, 1);
    k_aggmax<<<g4, 256, 0, stream>>>(Ht, offsets, entries, m_hi, m_lo, N);
    if (it < 7) {
      k_gru<2><<<g128, 256, 0, stream>>>(m_hi, m_lo, nullptr, nullptr,
                                         h_hi, h_lo, g0xf, g0hf, g0b,
                                         nullptr, h_hi, h_lo, N);
    } else {
      k_gru<4><<<g128, 256, 0, stream>>>(hinit_b, nullptr, m_hi, m_lo,
                                         h_hi, h_lo, g1xf, g1hf, g1b,
                                         out, nullptr, nullptr, N);
    }
  }
}

// Round 5
// 1189.330 us; speedup vs baseline: 11.0289x; 1.1267x over previous
//
#include <hip/hip_runtime.h>

typedef short v8s __attribute__((ext_vector_type(8)));
typedef float v4f __attribute__((ext_vector_type(4)));

__device__ __forceinline__ unsigned short f2bf(float x) {
  unsigned u = __float_as_uint(x);
  u = u + 0x7FFFu + ((u >> 16) & 1u);
  return (unsigned short)(u >> 16);
}
__device__ __forceinline__ float bf2f(unsigned short b) {
  return __uint_as_float(((unsigned)b) << 16);
}
__device__ __forceinline__ float sigmoidf_(float x) {
  return 1.f / (1.f + __expf(-x));
}
__device__ __forceinline__ float tanhf_(float x) {
  x = fminf(fmaxf(x, -20.f), 20.f);
  float e2 = __expf(2.f * x);
  return (e2 - 1.f) / (e2 + 1.f);
}

// ---------- merged weight prep ----------
// frag layout per weight: idx = ((p*nkc + kc)*nct + ct)*512 + lane*8 + j
// value: W[t][kc*32+(lane>>4)*8+j][ct*16+(lane&15)], p=0 hi, p=1 lo.
__device__ __forceinline__ void wprep_one(const float* W, unsigned short* O,
                                          int K, int J, int idx) {
  int nkc = K >> 5, nct = J >> 4;
  int j = idx & 7, lane = (idx >> 3) & 63;
  int rest = idx >> 9;
  int ct = rest % nct; rest /= nct;
  int kc = rest % nkc; rest /= nkc;
  int p = rest & 1, t = rest >> 1;
  int row = kc * 32 + (lane >> 4) * 8 + j;
  int col = ct * 16 + (lane & 15);
  float v = W[(size_t)t * K * J + (size_t)row * J + col];
  unsigned short hi = f2bf(v);
  O[idx] = p ? f2bf(v - bf2f(hi)) : hi;
}

__global__ void k_wprep_all(
    const float* eW0, const float* eW1, const float* projW,
    const float* g0Wx, const float* g0Wh, const float* g1Wx, const float* g1Wh,
    unsigned short* eW0f, unsigned short* eW1f, unsigned short* projf,
    unsigned short* g0xf, unsigned short* g0hf,
    unsigned short* g1xf, unsigned short* g1hf) {
  int rel = blockIdx.x * 256 + threadIdx.x;
  if (rel < 65536) { wprep_one(eW0, eW0f, 64, 64, rel); return; }
  rel -= 65536;
  if (rel < 65536) { wprep_one(eW1, eW1f, 64, 64, rel); return; }
  rel -= 65536;
  if (rel < 8192)  { wprep_one(projW, projf, 64, 64, rel); return; }
  rel -= 8192;
  if (rel < 24576) { wprep_one(g0Wx, g0xf, 64, 192, rel); return; }
  rel -= 24576;
  if (rel < 24576) { wprep_one(g0Wh, g0hf, 64, 192, rel); return; }
  rel -= 24576;
  if (rel < 49152) { wprep_one(g1Wx, g1xf, 128, 192, rel); return; }
  rel -= 49152;
  if (rel < 24576) { wprep_one(g1Wh, g1hf, 64, 192, rel); return; }
}

// ---------- CSR build ----------
__global__ void k_counts(const int* __restrict__ adj, int* __restrict__ counts, int E) {
  int e = blockIdx.x * 256 + threadIdx.x;
  if (e >= E) return;
  int t = blockIdx.y, t4 = t & 3;
  int a = adj[(size_t)(t4 * E + e) * 2], b = adj[(size_t)(t4 * E + e) * 2 + 1];
  int dst = (t < 4) ? b : a;
  atomicAdd(&counts[dst], 1);
}

__global__ __launch_bounds__(1024) void k_scan(const int* __restrict__ counts,
                                               int* __restrict__ offsets, int n) {
  __shared__ int part[1024];
  int tid = threadIdx.x;
  int chunk = (((n + 1023) >> 10) + 3) & ~3;
  int begin = tid * chunk;
  int end = min(begin + chunk, n);
  int s = 0;
  int i = begin;
  for (; i + 4 <= end; i += 4) {
    int4 v = *(const int4*)&counts[i];
    s += v.x + v.y + v.z + v.w;
  }
  for (; i < end; ++i) s += counts[i];
  part[tid] = s;
  __syncthreads();
  for (int off = 1; off < 1024; off <<= 1) {
    int v = (tid >= off) ? part[tid - off] : 0;
    __syncthreads();
    part[tid] += v;
    __syncthreads();
  }
  int run = part[tid] - s;
  i = begin;
  for (; i + 4 <= end; i += 4) {
    int4 c = *(const int4*)&counts[i];
    int4 o;
    o.x = run; o.y = run + c.x; o.z = o.y + c.y; o.w = o.z + c.z;
    *(int4*)&offsets[i] = o;
    run = o.w + c.w;
  }
  for (; i < end; ++i) { offsets[i] = run; run += counts[i]; }
  if (tid == 1023) offsets[n] = part[1023];
}

__global__ void k_fill(const int* __restrict__ adj, int* __restrict__ cursor,
                       int* __restrict__ entries, int E, int N) {
  int e = blockIdx.x * 256 + threadIdx.x;
  if (e >= E) return;
  int t = blockIdx.y, t4 = t & 3;
  int a = adj[(size_t)(t4 * E + e) * 2], b = adj[(size_t)(t4 * E + e) * 2 + 1];
  int src = (t < 4) ? a : b;
  int dst = (t < 4) ? b : a;
  int pos = atomicAdd(&cursor[dst], 1);
  entries[pos] = t * N + src;
}

// ---------- init: h = h_init = (mean embed) @ projW, fused gather+GEMM ----------
__global__ __launch_bounds__(256) void k_init(
    const int* __restrict__ toks, const float* __restrict__ embed,
    const unsigned short* __restrict__ projf,
    unsigned short* __restrict__ h_hi, unsigned short* __restrict__ h_lo,
    unsigned short* __restrict__ hinit_b, int N) {
  int tid = threadIdx.x;
  int wv = tid >> 6, lane = tid & 63;
  int lr = lane & 15, lg = lane >> 4;
  int m0 = blockIdx.x * 128 + wv * 32;
  v8s ah[2][2], al[2][2];  // [mt][kc]
#pragma unroll
  for (int mt = 0; mt < 2; ++mt) {
    int row = min(m0 + mt * 16 + lr, N - 1);
    int tk[5];
#pragma unroll
    for (int s = 0; s < 5; ++s) tk[s] = toks[row * 5 + s];
#pragma unroll
    for (int kc = 0; kc < 2; ++kc) {
      float v[8] = {};
#pragma unroll
      for (int s = 0; s < 5; ++s) {
        const float* er = &embed[(size_t)tk[s] * 64 + kc * 32 + lg * 8];
        float4 a = *(const float4*)er;
        float4 b = *(const float4*)(er + 4);
        v[0] += a.x; v[1] += a.y; v[2] += a.z; v[3] += a.w;
        v[4] += b.x; v[5] += b.y; v[6] += b.z; v[7] += b.w;
      }
#pragma unroll
      for (int j = 0; j < 8; ++j) {
        float x = v[j] * 0.2f;
        unsigned short hb = f2bf(x);
        ah[mt][kc][j] = (short)hb;
        al[mt][kc][j] = (short)f2bf(x - bf2f(hb));
      }
    }
  }
  v4f acc[2][4] = {};
#pragma unroll
  for (int kc = 0; kc < 2; ++kc) {
#pragma unroll
    for (int ct = 0; ct < 4; ++ct) {
      v8s bh = *(const v8s*)&projf[((size_t)(kc * 4 + ct)) * 512 + lane * 8];
      v8s bl = *(const v8s*)&projf[((size_t)((2 + kc) * 4 + ct)) * 512 + lane * 8];
#pragma unroll
      for (int mt = 0; mt < 2; ++mt) {
        acc[mt][ct] = __builtin_amdgcn_mfma_f32_16x16x32_bf16(ah[mt][kc], bh, acc[mt][ct], 0, 0, 0);
        acc[mt][ct] = __builtin_amdgcn_mfma_f32_16x16x32_bf16(al[mt][kc], bh, acc[mt][ct], 0, 0, 0);
        acc[mt][ct] = __builtin_amdgcn_mfma_f32_16x16x32_bf16(ah[mt][kc], bl, acc[mt][ct], 0, 0, 0);
      }
    }
  }
#pragma unroll
  for (int ct = 0; ct < 4; ++ct)
#pragma unroll
    for (int mt = 0; mt < 2; ++mt)
#pragma unroll
      for (int r = 0; r < 4; ++r) {
        int m = m0 + mt * 16 + lg * 4 + r;
        if (m >= N) continue;
        int col = ct * 16 + lr;
        float v = acc[mt][ct][r];
        unsigned short hb = f2bf(v);
        unsigned short lb = f2bf(v - bf2f(hb));
        h_hi[(size_t)m * 64 + col] = hb;
        h_lo[(size_t)m * 64 + col] = lb;
        hinit_b[(size_t)m * 64 + col] = hb;
      }
}

// ---------- transform: Ht[t][n] = h[n] @ W[t], bf16 output ----------
__global__ __launch_bounds__(256) void k_mm_t(
    const unsigned short* __restrict__ A0h, const unsigned short* __restrict__ A0l,
    const unsigned short* __restrict__ Wf, unsigned short* __restrict__ C16,
    int N) {
  int tid = threadIdx.x;
  int wv = tid >> 6, lane = tid & 63;
  int lr = lane & 15, lg = lane >> 4;
  const unsigned short* Wfb = Wf + (size_t)blockIdx.y * 8192;
  unsigned short* Cb = C16 + (size_t)blockIdx.y * N * 64;
  int m0 = blockIdx.x * 128 + wv * 32;
  v4f acc[2][4] = {};
#pragma unroll
  for (int kc = 0; kc < 2; ++kc) {
    v8s ah[2], al[2];
#pragma unroll
    for (int mt = 0; mt < 2; ++mt) {
      int row = min(m0 + mt * 16 + lr, N - 1);
      size_t off = (size_t)row * 64 + kc * 32 + lg * 8;
      ah[mt] = *(const v8s*)&A0h[off];
      al[mt] = *(const v8s*)&A0l[off];
    }
#pragma unroll
    for (int ct = 0; ct < 4; ++ct) {
      v8s bh = *(const v8s*)&Wfb[((size_t)(kc * 4 + ct)) * 512 + lane * 8];
      v8s bl = *(const v8s*)&Wfb[((size_t)((2 + kc) * 4 + ct)) * 512 + lane * 8];
#pragma unroll
      for (int mt = 0; mt < 2; ++mt) {
        acc[mt][ct] = __builtin_amdgcn_mfma_f32_16x16x32_bf16(ah[mt], bh, acc[mt][ct], 0, 0, 0);
        acc[mt][ct] = __builtin_amdgcn_mfma_f32_16x16x32_bf16(al[mt], bh, acc[mt][ct], 0, 0, 0);
        acc[mt][ct] = __builtin_amdgcn_mfma_f32_16x16x32_bf16(ah[mt], bl, acc[mt][ct], 0, 0, 0);
      }
    }
  }
#pragma unroll
  for (int ct = 0; ct < 4; ++ct)
#pragma unroll
    for (int mt = 0; mt < 2; ++mt)
#pragma unroll
      for (int r = 0; r < 4; ++r) {
        int m = m0 + mt * 16 + lg * 4 + r;
        if (m < N) Cb[(size_t)m * 64 + ct * 16 + lr] = f2bf(acc[mt][ct][r]);
      }
}

// ---------- segment-max over CSR (bf16 table, bf16 msg out) ----------
__global__ __launch_bounds__(256) void k_aggmax(
    const unsigned short* __restrict__ Htb, const int* __restrict__ offsets,
    const int* __restrict__ entries, unsigned short* __restrict__ mh, int N) {
  int w = threadIdx.x >> 6, lane = threadIdx.x & 63;
  int n = blockIdx.x * 4 + w;
  if (n >= N) return;
  int beg = offsets[n], end = offsets[n + 1];
  float m = -3.4e38f, m2 = -3.4e38f;
  int i = beg;
  for (; i + 4 <= end; i += 4) {
    int e0 = entries[i], e1 = entries[i + 1], e2 = entries[i + 2], e3 = entries[i + 3];
    float v0 = bf2f(Htb[(size_t)e0 * 64 + lane]);
    float v1 = bf2f(Htb[(size_t)e1 * 64 + lane]);
    float v2 = bf2f(Htb[(size_t)e2 * 64 + lane]);
    float v3 = bf2f(Htb[(size_t)e3 * 64 + lane]);
    m = fmaxf(m, fmaxf(v0, v1));
    m2 = fmaxf(m2, fmaxf(v2, v3));
  }
  m = fmaxf(m, m2);
  for (; i < end; ++i) m = fmaxf(m, bf2f(Htb[(size_t)entries[i] * 64 + lane]));
  float v = (end > beg) ? m : 0.f;
  mh[(size_t)n * 64 + lane] = f2bf(v);  // exact: v is a bf16 value or 0
}

// ---------- fused GRU ----------
// r = sig(xr+hr), u = sig(xu+hu), c = tanh(xc + r*hc); h' = u*h + (1-u)*c.
// x inputs are single-bf16 (msg / h_init); weights hi+lo (2 MFMA terms).
// h is hi/lo pair (3 MFMA terms); c-gate h-part in separate accumulators.
// NKCX=2: x = x0 (64 cols). NKCX=4: x = concat(x0, x1).
template <int NKCX>
__global__ __launch_bounds__(256) void k_gru(
    const unsigned short* __restrict__ x0, const unsigned short* __restrict__ x1,
    const unsigned short* __restrict__ hh, const unsigned short* __restrict__ hl,
    const unsigned short* __restrict__ Wxf, const unsigned short* __restrict__ Whf,
    const float* __restrict__ bias,
    float* outF, unsigned short* oh, unsigned short* ol, int N) {
  int tid = threadIdx.x;
  int wv = tid >> 6, lane = tid & 63;
  int lr = lane & 15, lg = lane >> 4;
  int m0 = blockIdx.x * 128 + wv * 32;
  v4f acc[2][12] = {};   // xr,xu,xc (+hr,hu merged)
  v4f acch[2][4] = {};   // hc separate
  // x @ Wx
#pragma unroll
  for (int kc = 0; kc < NKCX; ++kc) {
    const unsigned short* X = (NKCX == 4 && kc >= 2) ? x1 : x0;
    int kcl = kc & 1;
    v8s ax[2];
#pragma unroll
    for (int mt = 0; mt < 2; ++mt) {
      int row = min(m0 + mt * 16 + lr, N - 1);
      ax[mt] = *(const v8s*)&X[(size_t)row * 64 + kcl * 32 + lg * 8];
    }
#pragma unroll
    for (int ct = 0; ct < 12; ++ct) {
      v8s bh = *(const v8s*)&Wxf[((size_t)(kc * 12 + ct)) * 512 + lane * 8];
      v8s bl = *(const v8s*)&Wxf[((size_t)((NKCX + kc) * 12 + ct)) * 512 + lane * 8];
#pragma unroll
      for (int mt = 0; mt < 2; ++mt) {
        acc[mt][ct] = __builtin_amdgcn_mfma_f32_16x16x32_bf16(ax[mt], bh, acc[mt][ct], 0, 0, 0);
        acc[mt][ct] = __builtin_amdgcn_mfma_f32_16x16x32_bf16(ax[mt], bl, acc[mt][ct], 0, 0, 0);
      }
    }
  }
  // h @ Wh: r,u tiles (ct 0..7) merge into acc; c tiles (ct 8..11) -> acch
#pragma unroll
  for (int kc = 0; kc < 2; ++kc) {
    v8s ah[2], al[2];
#pragma unroll
    for (int mt = 0; mt < 2; ++mt) {
      int row = min(m0 + mt * 16 + lr, N - 1);
      size_t off = (size_t)row * 64 + kc * 32 + lg * 8;
      ah[mt] = *(const v8s*)&hh[off];
      al[mt] = *(const v8s*)&hl[off];
    }
#pragma unroll
    for (int ct = 0; ct < 12; ++ct) {
      v8s bh = *(const v8s*)&Whf[((size_t)(kc * 12 + ct)) * 512 + lane * 8];
      v8s bl = *(const v8s*)&Whf[((size_t)((2 + kc) * 12 + ct)) * 512 + lane * 8];
#pragma unroll
      for (int mt = 0; mt < 2; ++mt) {
        v4f* d = (ct < 8) ? &acc[mt][ct] : &acch[mt][ct - 8];
        *d = __builtin_amdgcn_mfma_f32_16x16x32_bf16(ah[mt], bh, *d, 0, 0, 0);
        *d = __builtin_amdgcn_mfma_f32_16x16x32_bf16(al[mt], bh, *d, 0, 0, 0);
        *d = __builtin_amdgcn_mfma_f32_16x16x32_bf16(ah[mt], bl, *d, 0, 0, 0);
      }
    }
  }
  // gate epilogue
#pragma unroll
  for (int mt = 0; mt < 2; ++mt)
#pragma unroll
    for (int ctg = 0; ctg < 4; ++ctg)
#pragma unroll
      for (int r = 0; r < 4; ++r) {
        int m = m0 + mt * 16 + lg * 4 + r;
        if (m >= N) continue;
        int col = ctg * 16 + lr;
        float hv = bf2f(hh[(size_t)m * 64 + col]) + bf2f(hl[(size_t)m * 64 + col]);
        float rr = sigmoidf_(acc[mt][ctg][r] + bias[col]);
        float uu = sigmoidf_(acc[mt][ctg + 4][r] + bias[64 + col]);
        float cc = tanhf_(acc[mt][ctg + 8][r] + bias[128 + col] + rr * acch[mt][ctg][r]);
        float ho = uu * hv + (1.f - uu) * cc;
        if (outF) outF[(size_t)m * 64 + col] = ho;
        if (oh) {
          unsigned short hb = f2bf(ho);
          oh[(size_t)m * 64 + col] = hb;
          ol[(size_t)m * 64 + col] = f2bf(ho - bf2f(hb));
        }
      }
}

extern "C" void kernel_launch(void* const* d_in, const int* in_sizes, int n_in,
                              void* d_out, int out_size, void* d_ws, size_t ws_size,
                              hipStream_t stream) {
  const int*   toks  = (const int*)d_in[0];
  const int*   adj   = (const int*)d_in[1];
  const float* embed = (const float*)d_in[2];
  const float* projW = (const float*)d_in[3];
  const float* eW0   = (const float*)d_in[4];
  const float* eW1   = (const float*)d_in[5];
  const float* g0Wx  = (const float*)d_in[6];
  const float* g0Wh  = (const float*)d_in[7];
  const float* g0b   = (const float*)d_in[8];
  const float* g1Wx  = (const float*)d_in[9];
  const float* g1Wh  = (const float*)d_in[10];
  const float* g1b   = (const float*)d_in[11];
  float* out = (float*)d_out;

  int N = in_sizes[0] / 5;
  int E = in_sizes[1] / 8;
  size_t ND = (size_t)N * 64;

  char* p = (char*)d_ws;
  unsigned short* Htb     = (unsigned short*)p; p += 8 * ND * 2;   // 61.4 MB
  unsigned short* h_hi    = (unsigned short*)p; p += ND * 2;
  unsigned short* h_lo    = (unsigned short*)p; p += ND * 2;
  unsigned short* hinit_b = (unsigned short*)p; p += ND * 2;
  unsigned short* m_hi    = (unsigned short*)p; p += ND * 2;
  int* offsets = (int*)p; p += (size_t)(N + 64) * sizeof(int);
  int* cnt_cur = (int*)p; p += (size_t)(N + 64) * sizeof(int);
  int* entries = (int*)p; p += (size_t)8 * E * sizeof(int);
  unsigned short* eW0f  = (unsigned short*)p; p += 65536 * 2;
  unsigned short* eW1f  = (unsigned short*)p; p += 65536 * 2;
  unsigned short* projf = (unsigned short*)p; p += 8192 * 2;
  unsigned short* g0xf  = (unsigned short*)p; p += 24576 * 2;
  unsigned short* g0hf  = (unsigned short*)p; p += 24576 * 2;
  unsigned short* g1xf  = (unsigned short*)p; p += 49152 * 2;
  unsigned short* g1hf  = (unsigned short*)p; p += 24576 * 2;
  if ((size_t)(p - (char*)d_ws) > ws_size) return;

  int g128 = (N + 127) / 128;
  int g4 = (N + 3) / 4;

  k_wprep_all<<<1024, 256, 0, stream>>>(eW0, eW1, projW, g0Wx, g0Wh, g1Wx, g1Wh,
                                        eW0f, eW1f, projf, g0xf, g0hf, g1xf, g1hf);
  hipMemsetAsync(cnt_cur, 0, (size_t)N * sizeof(int), stream);
  dim3 egrid((E + 255) / 256, 8);
  k_counts<<<egrid, 256, 0, stream>>>(adj, cnt_cur, E);
  k_init<<<g128, 256, 0, stream>>>(toks, embed, projf, h_hi, h_lo, hinit_b, N);
  k_scan<<<1, 1024, 0, stream>>>(cnt_cur, offsets, N);
  hipMemcpyAsync(cnt_cur, offsets, (size_t)N * sizeof(int),
                 hipMemcpyDeviceToDevice, stream);
  k_fill<<<egrid, 256, 0, stream>>>(adj, cnt_cur, entries, E, N);

  for (int it = 0; it < 8; ++it) {
    const unsigned short* ef = (it < 7) ? eW0f : eW1f;
    k_mm_t<<<dim3(g128, 8), 256, 0, stream>>>(h_hi, h_lo, ef, Htb, N);
    k_aggmax<<<g4, 256, 0, stream>>>(Htb, offsets, entries, m_hi, N);
    if (it < 7) {
      k_gru<2><<<g128, 256, 0, stream>>>(m_hi, nullptr, h_hi, h_lo,
                                         g0xf, g0hf, g0b,
                                         nullptr, h_hi, h_lo, N);
    } else {
      k_gru<4><<<g128, 256, 0, stream>>>(hinit_b, m_hi, h_hi, h_lo,
                                         g1xf, g1hf, g1b,
                                         out, nullptr, nullptr, N);
    }
  }
}

// Round 6
// 1187.923 us; speedup vs baseline: 11.0419x; 1.0012x over previous
//
#include <hip/hip_runtime.h>

typedef short v8s __attribute__((ext_vector_type(8)));
typedef float v4f __attribute__((ext_vector_type(4)));

__device__ __forceinline__ unsigned short f2bf(float x) {
  unsigned u = __float_as_uint(x);
  u = u + 0x7FFFu + ((u >> 16) & 1u);
  return (unsigned short)(u >> 16);
}
__device__ __forceinline__ float bf2f(unsigned short b) {
  return __uint_as_float(((unsigned)b) << 16);
}
__device__ __forceinline__ float sigmoidf_(float x) {
  return 1.f / (1.f + __expf(-x));
}
__device__ __forceinline__ float tanhf_(float x) {
  x = fminf(fmaxf(x, -20.f), 20.f);
  float e2 = __expf(2.f * x);
  return (e2 - 1.f) / (e2 + 1.f);
}

// ---------- merged weight prep ----------
// frag layout per weight: idx = ((p*nkc + kc)*nct + ct)*512 + lane*8 + j
// value: W[t][kc*32+(lane>>4)*8+j][ct*16+(lane&15)], p=0 hi, p=1 lo.
__device__ __forceinline__ void wprep_one(const float* W, unsigned short* O,
                                          int K, int J, int idx) {
  int nkc = K >> 5, nct = J >> 4;
  int j = idx & 7, lane = (idx >> 3) & 63;
  int rest = idx >> 9;
  int ct = rest % nct; rest /= nct;
  int kc = rest % nkc; rest /= nkc;
  int p = rest & 1, t = rest >> 1;
  int row = kc * 32 + (lane >> 4) * 8 + j;
  int col = ct * 16 + (lane & 15);
  float v = W[(size_t)t * K * J + (size_t)row * J + col];
  unsigned short hi = f2bf(v);
  O[idx] = p ? f2bf(v - bf2f(hi)) : hi;
}

__global__ void k_wprep_all(
    const float* eW0, const float* eW1, const float* projW,
    const float* g0Wx, const float* g0Wh, const float* g1Wx, const float* g1Wh,
    unsigned short* eW0f, unsigned short* eW1f, unsigned short* projf,
    unsigned short* g0xf, unsigned short* g0hf,
    unsigned short* g1xf, unsigned short* g1hf) {
  int rel = blockIdx.x * 256 + threadIdx.x;
  if (rel < 65536) { wprep_one(eW0, eW0f, 64, 64, rel); return; }
  rel -= 65536;
  if (rel < 65536) { wprep_one(eW1, eW1f, 64, 64, rel); return; }
  rel -= 65536;
  if (rel < 8192)  { wprep_one(projW, projf, 64, 64, rel); return; }
  rel -= 8192;
  if (rel < 24576) { wprep_one(g0Wx, g0xf, 64, 192, rel); return; }
  rel -= 24576;
  if (rel < 24576) { wprep_one(g0Wh, g0hf, 64, 192, rel); return; }
  rel -= 24576;
  if (rel < 49152) { wprep_one(g1Wx, g1xf, 128, 192, rel); return; }
  rel -= 49152;
  if (rel < 24576) { wprep_one(g1Wh, g1hf, 64, 192, rel); return; }
}

// ---------- embedding gather (coalesced: 64 lanes = 64 features) ----------
__global__ __launch_bounds__(256) void k_embed(
    const int* __restrict__ toks, const float* __restrict__ embed,
    unsigned short* __restrict__ eh, unsigned short* __restrict__ el, int N) {
  int w = threadIdx.x >> 6, lane = threadIdx.x & 63;
  int n = blockIdx.x * 4 + w;
  if (n >= N) return;
  float acc = 0.f;
#pragma unroll
  for (int s = 0; s < 5; ++s)
    acc += embed[(size_t)toks[n * 5 + s] * 64 + lane];
  float v = acc * 0.2f;
  unsigned short h = f2bf(v);
  eh[(size_t)n * 64 + lane] = h;
  el[(size_t)n * 64 + lane] = f2bf(v - bf2f(h));
}

// ---------- CSR build ----------
__global__ void k_counts(const int* __restrict__ adj, int* __restrict__ counts, int E) {
  int e = blockIdx.x * 256 + threadIdx.x;
  if (e >= E) return;
  int t = blockIdx.y, t4 = t & 3;
  int a = adj[(size_t)(t4 * E + e) * 2], b = adj[(size_t)(t4 * E + e) * 2 + 1];
  int dst = (t < 4) ? b : a;
  atomicAdd(&counts[dst], 1);
}

__global__ __launch_bounds__(1024) void k_scan(const int* __restrict__ counts,
                                               int* __restrict__ offsets, int n) {
  __shared__ int part[1024];
  int tid = threadIdx.x;
  int chunk = (((n + 1023) >> 10) + 3) & ~3;
  int begin = tid * chunk;
  int end = min(begin + chunk, n);
  int s = 0;
  int i = begin;
  for (; i + 4 <= end; i += 4) {
    int4 v = *(const int4*)&counts[i];
    s += v.x + v.y + v.z + v.w;
  }
  for (; i < end; ++i) s += counts[i];
  part[tid] = s;
  __syncthreads();
  for (int off = 1; off < 1024; off <<= 1) {
    int v = (tid >= off) ? part[tid - off] : 0;
    __syncthreads();
    part[tid] += v;
    __syncthreads();
  }
  int run = part[tid] - s;
  i = begin;
  for (; i + 4 <= end; i += 4) {
    int4 c = *(const int4*)&counts[i];
    int4 o;
    o.x = run; o.y = run + c.x; o.z = o.y + c.y; o.w = o.z + c.z;
    *(int4*)&offsets[i] = o;
    run = o.w + c.w;
  }
  for (; i < end; ++i) { offsets[i] = run; run += counts[i]; }
  if (tid == 1023) offsets[n] = part[1023];
}

__global__ void k_fill(const int* __restrict__ adj, int* __restrict__ cursor,
                       int* __restrict__ entries, int E, int N) {
  int e = blockIdx.x * 256 + threadIdx.x;
  if (e >= E) return;
  int t = blockIdx.y, t4 = t & 3;
  int a = adj[(size_t)(t4 * E + e) * 2], b = adj[(size_t)(t4 * E + e) * 2 + 1];
  int src = (t < 4) ? a : b;
  int dst = (t < 4) ? b : a;
  int pos = atomicAdd(&cursor[dst], 1);
  entries[pos] = t * N + src;
}

// ---------- proj GEMM: h_init = emb @ projW, epilogue writes hi/lo/hinit ----------
__global__ __launch_bounds__(256) void k_proj(
    const unsigned short* __restrict__ A0h, const unsigned short* __restrict__ A0l,
    const unsigned short* __restrict__ Wf,
    unsigned short* __restrict__ h_hi, unsigned short* __restrict__ h_lo,
    unsigned short* __restrict__ hinit_b, int N) {
  int tid = threadIdx.x;
  int wv = tid >> 6, lane = tid & 63;
  int lr = lane & 15, lg = lane >> 4;
  int m0 = blockIdx.x * 128 + wv * 32;
  v4f acc[2][4] = {};
#pragma unroll
  for (int kc = 0; kc < 2; ++kc) {
    v8s ah[2], al[2];
#pragma unroll
    for (int mt = 0; mt < 2; ++mt) {
      int row = min(m0 + mt * 16 + lr, N - 1);
      size_t off = (size_t)row * 64 + kc * 32 + lg * 8;
      ah[mt] = *(const v8s*)&A0h[off];
      al[mt] = *(const v8s*)&A0l[off];
    }
#pragma unroll
    for (int ct = 0; ct < 4; ++ct) {
      v8s bh = *(const v8s*)&Wf[((size_t)(kc * 4 + ct)) * 512 + lane * 8];
      v8s bl = *(const v8s*)&Wf[((size_t)((2 + kc) * 4 + ct)) * 512 + lane * 8];
#pragma unroll
      for (int mt = 0; mt < 2; ++mt) {
        acc[mt][ct] = __builtin_amdgcn_mfma_f32_16x16x32_bf16(ah[mt], bh, acc[mt][ct], 0, 0, 0);
        acc[mt][ct] = __builtin_amdgcn_mfma_f32_16x16x32_bf16(al[mt], bh, acc[mt][ct], 0, 0, 0);
        acc[mt][ct] = __builtin_amdgcn_mfma_f32_16x16x32_bf16(ah[mt], bl, acc[mt][ct], 0, 0, 0);
      }
    }
  }
#pragma unroll
  for (int ct = 0; ct < 4; ++ct)
#pragma unroll
    for (int mt = 0; mt < 2; ++mt)
#pragma unroll
      for (int r = 0; r < 4; ++r) {
        int m = m0 + mt * 16 + lg * 4 + r;
        if (m >= N) continue;
        int col = ct * 16 + lr;
        float v = acc[mt][ct][r];
        unsigned short hb = f2bf(v);
        h_hi[(size_t)m * 64 + col] = hb;
        h_lo[(size_t)m * 64 + col] = f2bf(v - bf2f(hb));
        hinit_b[(size_t)m * 64 + col] = hb;
      }
}

// ---------- transform: Ht[t][n] = h[n] @ W[t], bf16 output ----------
__global__ __launch_bounds__(256) void k_mm_t(
    const unsigned short* __restrict__ A0h, const unsigned short* __restrict__ A0l,
    const unsigned short* __restrict__ Wf, unsigned short* __restrict__ C16,
    int N) {
  int tid = threadIdx.x;
  int wv = tid >> 6, lane = tid & 63;
  int lr = lane & 15, lg = lane >> 4;
  const unsigned short* Wfb = Wf + (size_t)blockIdx.y * 8192;
  unsigned short* Cb = C16 + (size_t)blockIdx.y * N * 64;
  int m0 = blockIdx.x * 128 + wv * 32;
  v4f acc[2][4] = {};
#pragma unroll
  for (int kc = 0; kc < 2; ++kc) {
    v8s ah[2], al[2];
#pragma unroll
    for (int mt = 0; mt < 2; ++mt) {
      int row = min(m0 + mt * 16 + lr, N - 1);
      size_t off = (size_t)row * 64 + kc * 32 + lg * 8;
      ah[mt] = *(const v8s*)&A0h[off];
      al[mt] = *(const v8s*)&A0l[off];
    }
#pragma unroll
    for (int ct = 0; ct < 4; ++ct) {
      v8s bh = *(const v8s*)&Wfb[((size_t)(kc * 4 + ct)) * 512 + lane * 8];
      v8s bl = *(const v8s*)&Wfb[((size_t)((2 + kc) * 4 + ct)) * 512 + lane * 8];
#pragma unroll
      for (int mt = 0; mt < 2; ++mt) {
        acc[mt][ct] = __builtin_amdgcn_mfma_f32_16x16x32_bf16(ah[mt], bh, acc[mt][ct], 0, 0, 0);
        acc[mt][ct] = __builtin_amdgcn_mfma_f32_16x16x32_bf16(al[mt], bh, acc[mt][ct], 0, 0, 0);
        acc[mt][ct] = __builtin_amdgcn_mfma_f32_16x16x32_bf16(ah[mt], bl, acc[mt][ct], 0, 0, 0);
      }
    }
  }
#pragma unroll
  for (int ct = 0; ct < 4; ++ct)
#pragma unroll
    for (int mt = 0; mt < 2; ++mt)
#pragma unroll
      for (int r = 0; r < 4; ++r) {
        int m = m0 + mt * 16 + lg * 4 + r;
        if (m < N) Cb[(size_t)m * 64 + ct * 16 + lr] = f2bf(acc[mt][ct][r]);
      }
}

// ---------- segment-max over CSR (bf16 table, bf16 msg out) ----------
__global__ __launch_bounds__(256) void k_aggmax(
    const unsigned short* __restrict__ Htb, const int* __restrict__ offsets,
    const int* __restrict__ entries, unsigned short* __restrict__ mh, int N) {
  int w = threadIdx.x >> 6, lane = threadIdx.x & 63;
  int n = blockIdx.x * 4 + w;
  if (n >= N) return;
  int beg = offsets[n], end = offsets[n + 1];
  float m = -3.4e38f, m2 = -3.4e38f;
  int i = beg;
  for (; i + 4 <= end; i += 4) {
    int e0 = entries[i], e1 = entries[i + 1], e2 = entries[i + 2], e3 = entries[i + 3];
    float v0 = bf2f(Htb[(size_t)e0 * 64 + lane]);
    float v1 = bf2f(Htb[(size_t)e1 * 64 + lane]);
    float v2 = bf2f(Htb[(size_t)e2 * 64 + lane]);
    float v3 = bf2f(Htb[(size_t)e3 * 64 + lane]);
    m = fmaxf(m, fmaxf(v0, v1));
    m2 = fmaxf(m2, fmaxf(v2, v3));
  }
  m = fmaxf(m, m2);
  for (; i < end; ++i) m = fmaxf(m, bf2f(Htb[(size_t)entries[i] * 64 + lane]));
  float v = (end > beg) ? m : 0.f;
  mh[(size_t)n * 64 + lane] = f2bf(v);  // exact: v is a bf16 value or 0
}

// ---------- fused GRU ----------
// r = sig(xr+hr), u = sig(xu+hu), c = tanh(xc + r*hc); h' = u*h + (1-u)*c.
// x inputs are single-bf16 (msg / h_init); weights hi+lo (2 MFMA terms).
// h is hi/lo pair (3 MFMA terms); c-gate h-part in separate accumulators.
// NKCX=2: x = x0 (64 cols). NKCX=4: x = concat(x0, x1).
template <int NKCX>
__global__ __launch_bounds__(256) void k_gru(
    const unsigned short* __restrict__ x0, const unsigned short* __restrict__ x1,
    const unsigned short* __restrict__ hh, const unsigned short* __restrict__ hl,
    const unsigned short* __restrict__ Wxf, const unsigned short* __restrict__ Whf,
    const float* __restrict__ bias,
    float* outF, unsigned short* oh, unsigned short* ol, int N) {
  int tid = threadIdx.x;
  int wv = tid >> 6, lane = tid & 63;
  int lr = lane & 15, lg = lane >> 4;
  int m0 = blockIdx.x * 128 + wv * 32;
  v4f acc[2][12] = {};   // xr,xu,xc (+hr,hu merged)
  v4f acch[2][4] = {};   // hc separate
  // x @ Wx
#pragma unroll
  for (int kc = 0; kc < NKCX; ++kc) {
    const unsigned short* X = (NKCX == 4 && kc >= 2) ? x1 : x0;
    int kcl = kc & 1;
    v8s ax[2];
#pragma unroll
    for (int mt = 0; mt < 2; ++mt) {
      int row = min(m0 + mt * 16 + lr, N - 1);
      ax[mt] = *(const v8s*)&X[(size_t)row * 64 + kcl * 32 + lg * 8];
    }
#pragma unroll
    for (int ct = 0; ct < 12; ++ct) {
      v8s bh = *(const v8s*)&Wxf[((size_t)(kc * 12 + ct)) * 512 + lane * 8];
      v8s bl = *(const v8s*)&Wxf[((size_t)((NKCX + kc) * 12 + ct)) * 512 + lane * 8];
#pragma unroll
      for (int mt = 0; mt < 2; ++mt) {
        acc[mt][ct] = __builtin_amdgcn_mfma_f32_16x16x32_bf16(ax[mt], bh, acc[mt][ct], 0, 0, 0);
        acc[mt][ct] = __builtin_amdgcn_mfma_f32_16x16x32_bf16(ax[mt], bl, acc[mt][ct], 0, 0, 0);
      }
    }
  }
  // h @ Wh: r,u tiles (ct 0..7) merge into acc; c tiles (ct 8..11) -> acch
#pragma unroll
  for (int kc = 0; kc < 2; ++kc) {
    v8s ah[2], al[2];
#pragma unroll
    for (int mt = 0; mt < 2; ++mt) {
      int row = min(m0 + mt * 16 + lr, N - 1);
      size_t off = (size_t)row * 64 + kc * 32 + lg * 8;
      ah[mt] = *(const v8s*)&hh[off];
      al[mt] = *(const v8s*)&hl[off];
    }
#pragma unroll
    for (int ct = 0; ct < 12; ++ct) {
      v8s bh = *(const v8s*)&Whf[((size_t)(kc * 12 + ct)) * 512 + lane * 8];
      v8s bl = *(const v8s*)&Whf[((size_t)((2 + kc) * 12 + ct)) * 512 + lane * 8];
#pragma unroll
      for (int mt = 0; mt < 2; ++mt) {
        v4f* d = (ct < 8) ? &acc[mt][ct] : &acch[mt][ct - 8];
        *d = __builtin_amdgcn_mfma_f32_16x16x32_bf16(ah[mt], bh, *d, 0, 0, 0);
        *d = __builtin_amdgcn_mfma_f32_16x16x32_bf16(al[mt], bh, *d, 0, 0, 0);
        *d = __builtin_amdgcn_mfma_f32_16x16x32_bf16(ah[mt], bl, *d, 0, 0, 0);
      }
    }
  }
  // gate epilogue
#pragma unroll
  for (int mt = 0; mt < 2; ++mt)
#pragma unroll
    for (int ctg = 0; ctg < 4; ++ctg)
#pragma unroll
      for (int r = 0; r < 4; ++r) {
        int m = m0 + mt * 16 + lg * 4 + r;
        if (m >= N) continue;
        int col = ctg * 16 + lr;
        float hv = bf2f(hh[(size_t)m * 64 + col]) + bf2f(hl[(size_t)m * 64 + col]);
        float rr = sigmoidf_(acc[mt][ctg][r] + bias[col]);
        float uu = sigmoidf_(acc[mt][ctg + 4][r] + bias[64 + col]);
        float cc = tanhf_(acc[mt][ctg + 8][r] + bias[128 + col] + rr * acch[mt][ctg][r]);
        float ho = uu * hv + (1.f - uu) * cc;
        if (outF) outF[(size_t)m * 64 + col] = ho;
        if (oh) {
          unsigned short hb = f2bf(ho);
          oh[(size_t)m * 64 + col] = hb;
          ol[(size_t)m * 64 + col] = f2bf(ho - bf2f(hb));
        }
      }
}

extern "C" void kernel_launch(void* const* d_in, const int* in_sizes, int n_in,
                              void* d_out, int out_size, void* d_ws, size_t ws_size,
                              hipStream_t stream) {
  const int*   toks  = (const int*)d_in[0];
  const int*   adj   = (const int*)d_in[1];
  const float* embed = (const float*)d_in[2];
  const float* projW = (const float*)d_in[3];
  const float* eW0   = (const float*)d_in[4];
  const float* eW1   = (const float*)d_in[5];
  const float* g0Wx  = (const float*)d_in[6];
  const float* g0Wh  = (const float*)d_in[7];
  const float* g0b   = (const float*)d_in[8];
  const float* g1Wx  = (const float*)d_in[9];
  const float* g1Wh  = (const float*)d_in[10];
  const float* g1b   = (const float*)d_in[11];
  float* out = (float*)d_out;

  int N = in_sizes[0] / 5;
  int E = in_sizes[1] / 8;
  size_t ND = (size_t)N * 64;

  char* p = (char*)d_ws;
  unsigned short* Htb     = (unsigned short*)p; p += 8 * ND * 2;   // 61.4 MB
  unsigned short* h_hi    = (unsigned short*)p; p += ND * 2;
  unsigned short* h_lo    = (unsigned short*)p; p += ND * 2;
  unsigned short* hinit_b = (unsigned short*)p; p += ND * 2;
  unsigned short* m_hi    = (unsigned short*)p; p += ND * 2;
  int* offsets = (int*)p; p += (size_t)(N + 64) * sizeof(int);
  int* cnt_cur = (int*)p; p += (size_t)(N + 64) * sizeof(int);
  int* entries = (int*)p; p += (size_t)8 * E * sizeof(int);
  unsigned short* eW0f  = (unsigned short*)p; p += 65536 * 2;
  unsigned short* eW1f  = (unsigned short*)p; p += 65536 * 2;
  unsigned short* projf = (unsigned short*)p; p += 8192 * 2;
  unsigned short* g0xf  = (unsigned short*)p; p += 24576 * 2;
  unsigned short* g0hf  = (unsigned short*)p; p += 24576 * 2;
  unsigned short* g1xf  = (unsigned short*)p; p += 49152 * 2;
  unsigned short* g1hf  = (unsigned short*)p; p += 24576 * 2;
  if ((size_t)(p - (char*)d_ws) > ws_size) return;

  // init-phase aliases inside Htb (used before the first transform)
  unsigned short* emb_h = Htb;
  unsigned short* emb_l = Htb + ND;

  int g128 = (N + 127) / 128;
  int g4 = (N + 3) / 4;

  k_wprep_all<<<1024, 256, 0, stream>>>(eW0, eW1, projW, g0Wx, g0Wh, g1Wx, g1Wh,
                                        eW0f, eW1f, projf, g0xf, g0hf, g1xf, g1hf);
  hipMemsetAsync(cnt_cur, 0, (size_t)N * sizeof(int), stream);
  dim3 egrid((E + 255) / 256, 8);
  k_counts<<<egrid, 256, 0, stream>>>(adj, cnt_cur, E);
  k_embed<<<g4, 256, 0, stream>>>(toks, embed, emb_h, emb_l, N);
  k_proj<<<g128, 256, 0, stream>>>(emb_h, emb_l, projf, h_hi, h_lo, hinit_b, N);
  k_scan<<<1, 1024, 0, stream>>>(cnt_cur, offsets, N);
  hipMemcpyAsync(cnt_cur, offsets, (size_t)N * sizeof(int),
                 hipMemcpyDeviceToDevice, stream);
  k_fill<<<egrid, 256, 0, stream>>>(adj, cnt_cur, entries, E, N);

  for (int it = 0; it < 8; ++it) {
    const unsigned short* ef = (it < 7) ? eW0f : eW1f;
    k_mm_t<<<dim3(g128, 8), 256, 0, stream>>>(h_hi, h_lo, ef, Htb, N);
    k_aggmax<<<g4, 256, 0, stream>>>(Htb, offsets, entries, m_hi, N);
    if (it < 7) {
      k_gru<2><<<g128, 256, 0, stream>>>(m_hi, nullptr, h_hi, h_lo,
                                         g0xf, g0hf, g0b,
                                         nullptr, h_hi, h_lo, N);
    } else {
      k_gru<4><<<g128, 256, 0, stream>>>(hinit_b, m_hi, h_hi, h_lo,
                                         g1xf, g1hf, g1b,
                                         out, nullptr, nullptr, N);
    }
  }
}

// Round 7
// 1112.130 us; speedup vs baseline: 11.7944x; 1.0682x over previous
//
#include <hip/hip_runtime.h>

typedef short v8s __attribute__((ext_vector_type(8)));
typedef float v4f __attribute__((ext_vector_type(4)));

__device__ __forceinline__ unsigned short f2bf(float x) {
  unsigned u = __float_as_uint(x);
  u = u + 0x7FFFu + ((u >> 16) & 1u);
  return (unsigned short)(u >> 16);
}
__device__ __forceinline__ float bf2f(unsigned short b) {
  return __uint_as_float(((unsigned)b) << 16);
}
__device__ __forceinline__ float sigmoidf_(float x) {
  return 1.f / (1.f + __expf(-x));
}
__device__ __forceinline__ float tanhf_(float x) {
  x = fminf(fmaxf(x, -20.f), 20.f);
  float e2 = __expf(2.f * x);
  return (e2 - 1.f) / (e2 + 1.f);
}

// ---------- merged weight prep ----------
// frag layout per weight: idx = ((p*nkc + kc)*nct + ct)*512 + lane*8 + j
// value: W[t][kc*32+(lane>>4)*8+j][ct*16+(lane&15)], p=0 hi, p=1 lo.
__device__ __forceinline__ void wprep_one(const float* W, unsigned short* O,
                                          int K, int J, int idx) {
  int nkc = K >> 5, nct = J >> 4;
  int j = idx & 7, lane = (idx >> 3) & 63;
  int rest = idx >> 9;
  int ct = rest % nct; rest /= nct;
  int kc = rest % nkc; rest /= nkc;
  int p = rest & 1, t = rest >> 1;
  int row = kc * 32 + (lane >> 4) * 8 + j;
  int col = ct * 16 + (lane & 15);
  float v = W[(size_t)t * K * J + (size_t)row * J + col];
  unsigned short hi = f2bf(v);
  O[idx] = p ? f2bf(v - bf2f(hi)) : hi;
}

__global__ void k_wprep_all(
    const float* eW0, const float* eW1, const float* projW,
    const float* g0Wx, const float* g0Wh, const float* g1Wx, const float* g1Wh,
    unsigned short* eW0f, unsigned short* eW1f, unsigned short* projf,
    unsigned short* g0xf, unsigned short* g0hf,
    unsigned short* g1xf, unsigned short* g1hf) {
  int rel = blockIdx.x * 256 + threadIdx.x;
  if (rel < 65536) { wprep_one(eW0, eW0f, 64, 64, rel); return; }
  rel -= 65536;
  if (rel < 65536) { wprep_one(eW1, eW1f, 64, 64, rel); return; }
  rel -= 65536;
  if (rel < 8192)  { wprep_one(projW, projf, 64, 64, rel); return; }
  rel -= 8192;
  if (rel < 24576) { wprep_one(g0Wx, g0xf, 64, 192, rel); return; }
  rel -= 24576;
  if (rel < 24576) { wprep_one(g0Wh, g0hf, 64, 192, rel); return; }
  rel -= 24576;
  if (rel < 49152) { wprep_one(g1Wx, g1xf, 128, 192, rel); return; }
  rel -= 49152;
  if (rel < 24576) { wprep_one(g1Wh, g1hf, 64, 192, rel); return; }
}

// ---------- embedding gather (coalesced: 64 lanes = 64 features) ----------
__global__ __launch_bounds__(256) void k_embed(
    const int* __restrict__ toks, const float* __restrict__ embed,
    unsigned short* __restrict__ eh, unsigned short* __restrict__ el, int N) {
  int w = threadIdx.x >> 6, lane = threadIdx.x & 63;
  int n = blockIdx.x * 4 + w;
  if (n >= N) return;
  float acc = 0.f;
#pragma unroll
  for (int s = 0; s < 5; ++s)
    acc += embed[(size_t)toks[n * 5 + s] * 64 + lane];
  float v = acc * 0.2f;
  unsigned short h = f2bf(v);
  eh[(size_t)n * 64 + lane] = h;
  el[(size_t)n * 64 + lane] = f2bf(v - bf2f(h));
}

// ---------- CSR build: each thread handles fwd+bwd of one edge ----------
__global__ void k_counts(const int* __restrict__ adj, int* __restrict__ counts, int E) {
  int e = blockIdx.x * 256 + threadIdx.x;
  if (e >= E) return;
  int t4 = blockIdx.y;
  int2 ab = *(const int2*)&adj[(size_t)(t4 * E + e) * 2];
  atomicAdd(&counts[ab.y], 1);  // fwd type t4: dst = b
  atomicAdd(&counts[ab.x], 1);  // bwd type t4+4: dst = a
}

// scan counts -> offsets[0..n]; also writes cursor copy (may alias counts).
__global__ __launch_bounds__(1024) void k_scan(const int* __restrict__ counts,
                                               int* __restrict__ offsets,
                                               int* __restrict__ cursor, int n) {
  __shared__ int part[1024];
  int tid = threadIdx.x;
  int chunk = (((n + 1023) >> 10) + 3) & ~3;
  int begin = tid * chunk;
  int end = min(begin + chunk, n);
  int s = 0;
  int i = begin;
  for (; i + 4 <= end; i += 4) {
    int4 v = *(const int4*)&counts[i];
    s += v.x + v.y + v.z + v.w;
  }
  for (; i < end; ++i) s += counts[i];
  part[tid] = s;
  __syncthreads();
  for (int off = 1; off < 1024; off <<= 1) {
    int v = (tid >= off) ? part[tid - off] : 0;
    __syncthreads();
    part[tid] += v;
    __syncthreads();
  }
  int run = part[tid] - s;
  i = begin;
  for (; i + 4 <= end; i += 4) {
    int4 c = *(const int4*)&counts[i];
    int4 o;
    o.x = run; o.y = run + c.x; o.z = o.y + c.y; o.w = o.z + c.z;
    *(int4*)&offsets[i] = o;
    *(int4*)&cursor[i] = o;
    run = o.w + c.w;
  }
  for (; i < end; ++i) {
    offsets[i] = run; cursor[i] = run; run += counts[i];
  }
  if (tid == 1023) offsets[n] = part[1023];
}

__global__ void k_fill(const int* __restrict__ adj, int* __restrict__ cursor,
                       int* __restrict__ entries, int E, int N) {
  int e = blockIdx.x * 256 + threadIdx.x;
  if (e >= E) return;
  int t4 = blockIdx.y;
  int2 ab = *(const int2*)&adj[(size_t)(t4 * E + e) * 2];
  int p1 = atomicAdd(&cursor[ab.y], 1);
  entries[p1] = t4 * N + ab.x;          // fwd: src=a, dst=b
  int p2 = atomicAdd(&cursor[ab.x], 1);
  entries[p2] = (t4 + 4) * N + ab.y;    // bwd: src=b, dst=a
}

// ---------- proj GEMM: h_init = emb @ projW, epilogue writes hi/lo/hinit ----------
__global__ __launch_bounds__(256) void k_proj(
    const unsigned short* __restrict__ A0h, const unsigned short* __restrict__ A0l,
    const unsigned short* __restrict__ Wf,
    unsigned short* __restrict__ h_hi, unsigned short* __restrict__ h_lo,
    unsigned short* __restrict__ hinit_b, int N) {
  int tid = threadIdx.x;
  int wv = tid >> 6, lane = tid & 63;
  int lr = lane & 15, lg = lane >> 4;
  int m0 = blockIdx.x * 128 + wv * 32;
  v4f acc[2][4] = {};
#pragma unroll
  for (int kc = 0; kc < 2; ++kc) {
    v8s ah[2], al[2];
#pragma unroll
    for (int mt = 0; mt < 2; ++mt) {
      int row = min(m0 + mt * 16 + lr, N - 1);
      size_t off = (size_t)row * 64 + kc * 32 + lg * 8;
      ah[mt] = *(const v8s*)&A0h[off];
      al[mt] = *(const v8s*)&A0l[off];
    }
#pragma unroll
    for (int ct = 0; ct < 4; ++ct) {
      v8s bh = *(const v8s*)&Wf[((size_t)(kc * 4 + ct)) * 512 + lane * 8];
      v8s bl = *(const v8s*)&Wf[((size_t)((2 + kc) * 4 + ct)) * 512 + lane * 8];
#pragma unroll
      for (int mt = 0; mt < 2; ++mt) {
        acc[mt][ct] = __builtin_amdgcn_mfma_f32_16x16x32_bf16(ah[mt], bh, acc[mt][ct], 0, 0, 0);
        acc[mt][ct] = __builtin_amdgcn_mfma_f32_16x16x32_bf16(al[mt], bh, acc[mt][ct], 0, 0, 0);
        acc[mt][ct] = __builtin_amdgcn_mfma_f32_16x16x32_bf16(ah[mt], bl, acc[mt][ct], 0, 0, 0);
      }
    }
  }
#pragma unroll
  for (int ct = 0; ct < 4; ++ct)
#pragma unroll
    for (int mt = 0; mt < 2; ++mt)
#pragma unroll
      for (int r = 0; r < 4; ++r) {
        int m = m0 + mt * 16 + lg * 4 + r;
        if (m >= N) continue;
        int col = ct * 16 + lr;
        float v = acc[mt][ct][r];
        unsigned short hb = f2bf(v);
        h_hi[(size_t)m * 64 + col] = hb;
        h_lo[(size_t)m * 64 + col] = f2bf(v - bf2f(hb));
        hinit_b[(size_t)m * 64 + col] = hb;
      }
}

// ---------- transform: Ht[t][n] = h[n] @ W[t], 2 types per block ----------
__global__ __launch_bounds__(256) void k_mm_t(
    const unsigned short* __restrict__ A0h, const unsigned short* __restrict__ A0l,
    const unsigned short* __restrict__ Wf, unsigned short* __restrict__ C16,
    int N) {
  int tid = threadIdx.x;
  int wv = tid >> 6, lane = tid & 63;
  int lr = lane & 15, lg = lane >> 4;
  int y = blockIdx.y;  // types y and y+4
  const unsigned short* W0 = Wf + (size_t)y * 8192;
  const unsigned short* W1 = Wf + (size_t)(y + 4) * 8192;
  unsigned short* C0 = C16 + (size_t)y * N * 64;
  unsigned short* C1 = C16 + (size_t)(y + 4) * N * 64;
  int m0 = blockIdx.x * 128 + wv * 32;
  v4f acc0[2][4] = {}, acc1[2][4] = {};
#pragma unroll
  for (int kc = 0; kc < 2; ++kc) {
    v8s ah[2], al[2];
#pragma unroll
    for (int mt = 0; mt < 2; ++mt) {
      int row = min(m0 + mt * 16 + lr, N - 1);
      size_t off = (size_t)row * 64 + kc * 32 + lg * 8;
      ah[mt] = *(const v8s*)&A0h[off];
      al[mt] = *(const v8s*)&A0l[off];
    }
#pragma unroll
    for (int ct = 0; ct < 4; ++ct) {
      v8s bh0 = *(const v8s*)&W0[((size_t)(kc * 4 + ct)) * 512 + lane * 8];
      v8s bl0 = *(const v8s*)&W0[((size_t)((2 + kc) * 4 + ct)) * 512 + lane * 8];
      v8s bh1 = *(const v8s*)&W1[((size_t)(kc * 4 + ct)) * 512 + lane * 8];
      v8s bl1 = *(const v8s*)&W1[((size_t)((2 + kc) * 4 + ct)) * 512 + lane * 8];
#pragma unroll
      for (int mt = 0; mt < 2; ++mt) {
        acc0[mt][ct] = __builtin_amdgcn_mfma_f32_16x16x32_bf16(ah[mt], bh0, acc0[mt][ct], 0, 0, 0);
        acc0[mt][ct] = __builtin_amdgcn_mfma_f32_16x16x32_bf16(al[mt], bh0, acc0[mt][ct], 0, 0, 0);
        acc0[mt][ct] = __builtin_amdgcn_mfma_f32_16x16x32_bf16(ah[mt], bl0, acc0[mt][ct], 0, 0, 0);
        acc1[mt][ct] = __builtin_amdgcn_mfma_f32_16x16x32_bf16(ah[mt], bh1, acc1[mt][ct], 0, 0, 0);
        acc1[mt][ct] = __builtin_amdgcn_mfma_f32_16x16x32_bf16(al[mt], bh1, acc1[mt][ct], 0, 0, 0);
        acc1[mt][ct] = __builtin_amdgcn_mfma_f32_16x16x32_bf16(ah[mt], bl1, acc1[mt][ct], 0, 0, 0);
      }
    }
  }
#pragma unroll
  for (int ct = 0; ct < 4; ++ct)
#pragma unroll
    for (int mt = 0; mt < 2; ++mt)
#pragma unroll
      for (int r = 0; r < 4; ++r) {
        int m = m0 + mt * 16 + lg * 4 + r;
        if (m < N) {
          C0[(size_t)m * 64 + ct * 16 + lr] = f2bf(acc0[mt][ct][r]);
          C1[(size_t)m * 64 + ct * 16 + lr] = f2bf(acc1[mt][ct][r]);
        }
      }
}

// ---------- segment-max: 4 entries per load inst (ushort4 per lane) ----------
// lane group g=lane>>4 handles entry i+g; 16 lanes x 8B cover one 128B line.
__global__ __launch_bounds__(256) void k_aggmax(
    const unsigned short* __restrict__ Htb, const int* __restrict__ offsets,
    const int* __restrict__ entries, unsigned short* __restrict__ mh, int N) {
  int w = threadIdx.x >> 6, lane = threadIdx.x & 63;
  int n = blockIdx.x * 4 + w;
  if (n >= N) return;
  int beg = offsets[n], end = offsets[n + 1];
  int g = lane >> 4, q = lane & 15;
  float a0 = -3.4e38f, a1 = a0, a2 = a0, a3 = a0;
  float b0 = a0, b1 = a0, b2 = a0, b3 = a0;
  int i = beg;
  for (; i + 8 <= end; i += 8) {
    int eA = entries[i + g];
    int eB = entries[i + 4 + g];
    ushort4 va = *(const ushort4*)&Htb[(size_t)eA * 64 + q * 4];
    ushort4 vb = *(const ushort4*)&Htb[(size_t)eB * 64 + q * 4];
    a0 = fmaxf(a0, bf2f(va.x)); a1 = fmaxf(a1, bf2f(va.y));
    a2 = fmaxf(a2, bf2f(va.z)); a3 = fmaxf(a3, bf2f(va.w));
    b0 = fmaxf(b0, bf2f(vb.x)); b1 = fmaxf(b1, bf2f(vb.y));
    b2 = fmaxf(b2, bf2f(vb.z)); b3 = fmaxf(b3, bf2f(vb.w));
  }
  for (; i < end; i += 4) {
    int idx = min(i + g, end - 1);  // clamped dup loads are harmless for max
    int e = entries[idx];
    ushort4 va = *(const ushort4*)&Htb[(size_t)e * 64 + q * 4];
    a0 = fmaxf(a0, bf2f(va.x)); a1 = fmaxf(a1, bf2f(va.y));
    a2 = fmaxf(a2, bf2f(va.z)); a3 = fmaxf(a3, bf2f(va.w));
  }
  a0 = fmaxf(a0, b0); a1 = fmaxf(a1, b1); a2 = fmaxf(a2, b2); a3 = fmaxf(a3, b3);
  a0 = fmaxf(a0, __shfl_xor(a0, 16)); a1 = fmaxf(a1, __shfl_xor(a1, 16));
  a2 = fmaxf(a2, __shfl_xor(a2, 16)); a3 = fmaxf(a3, __shfl_xor(a3, 16));
  a0 = fmaxf(a0, __shfl_xor(a0, 32)); a1 = fmaxf(a1, __shfl_xor(a1, 32));
  a2 = fmaxf(a2, __shfl_xor(a2, 32)); a3 = fmaxf(a3, __shfl_xor(a3, 32));
  if (g == 0) {
    ushort4 o;
    if (end > beg) {
      o.x = f2bf(a0); o.y = f2bf(a1); o.z = f2bf(a2); o.w = f2bf(a3);
    } else {
      o.x = 0; o.y = 0; o.z = 0; o.w = 0;
    }
    *(ushort4*)&mh[(size_t)n * 64 + q * 4] = o;
  }
}

// ---------- fused GRU ----------
// r = sig(xr+hr), u = sig(xu+hu), c = tanh(xc + r*hc); h' = u*h + (1-u)*c.
// x inputs single-bf16; weights hi+lo (2 MFMA terms); h hi/lo pair (3 terms).
// NKCX=2: x = x0 (64 cols). NKCX=4: x = concat(x0, x1).
template <int NKCX>
__global__ __launch_bounds__(256) void k_gru(
    const unsigned short* __restrict__ x0, const unsigned short* __restrict__ x1,
    const unsigned short* __restrict__ hh, const unsigned short* __restrict__ hl,
    const unsigned short* __restrict__ Wxf, const unsigned short* __restrict__ Whf,
    const float* __restrict__ bias,
    float* outF, unsigned short* oh, unsigned short* ol, int N) {
  int tid = threadIdx.x;
  int wv = tid >> 6, lane = tid & 63;
  int lr = lane & 15, lg = lane >> 4;
  int m0 = blockIdx.x * 128 + wv * 32;
  v4f acc[2][12] = {};   // xr,xu,xc (+hr,hu merged)
  v4f acch[2][4] = {};   // hc separate
#pragma unroll
  for (int kc = 0; kc < NKCX; ++kc) {
    const unsigned short* X = (NKCX == 4 && kc >= 2) ? x1 : x0;
    int kcl = kc & 1;
    v8s ax[2];
#pragma unroll
    for (int mt = 0; mt < 2; ++mt) {
      int row = min(m0 + mt * 16 + lr, N - 1);
      ax[mt] = *(const v8s*)&X[(size_t)row * 64 + kcl * 32 + lg * 8];
    }
#pragma unroll
    for (int ct = 0; ct < 12; ++ct) {
      v8s bh = *(const v8s*)&Wxf[((size_t)(kc * 12 + ct)) * 512 + lane * 8];
      v8s bl = *(const v8s*)&Wxf[((size_t)((NKCX + kc) * 12 + ct)) * 512 + lane * 8];
#pragma unroll
      for (int mt = 0; mt < 2; ++mt) {
        acc[mt][ct] = __builtin_amdgcn_mfma_f32_16x16x32_bf16(ax[mt], bh, acc[mt][ct], 0, 0, 0);
        acc[mt][ct] = __builtin_amdgcn_mfma_f32_16x16x32_bf16(ax[mt], bl, acc[mt][ct], 0, 0, 0);
      }
    }
  }
#pragma unroll
  for (int kc = 0; kc < 2; ++kc) {
    v8s ah[2], al[2];
#pragma unroll
    for (int mt = 0; mt < 2; ++mt) {
      int row = min(m0 + mt * 16 + lr, N - 1);
      size_t off = (size_t)row * 64 + kc * 32 + lg * 8;
      ah[mt] = *(const v8s*)&hh[off];
      al[mt] = *(const v8s*)&hl[off];
    }
#pragma unroll
    for (int ct = 0; ct < 12; ++ct) {
      v8s bh = *(const v8s*)&Whf[((size_t)(kc * 12 + ct)) * 512 + lane * 8];
      v8s bl = *(const v8s*)&Whf[((size_t)((2 + kc) * 12 + ct)) * 512 + lane * 8];
#pragma unroll
      for (int mt = 0; mt < 2; ++mt) {
        v4f* d = (ct < 8) ? &acc[mt][ct] : &acch[mt][ct - 8];
        *d = __builtin_amdgcn_mfma_f32_16x16x32_bf16(ah[mt], bh, *d, 0, 0, 0);
        *d = __builtin_amdgcn_mfma_f32_16x16x32_bf16(al[mt], bh, *d, 0, 0, 0);
        *d = __builtin_amdgcn_mfma_f32_16x16x32_bf16(ah[mt], bl, *d, 0, 0, 0);
      }
    }
  }
#pragma unroll
  for (int mt = 0; mt < 2; ++mt)
#pragma unroll
    for (int ctg = 0; ctg < 4; ++ctg)
#pragma unroll
      for (int r = 0; r < 4; ++r) {
        int m = m0 + mt * 16 + lg * 4 + r;
        if (m >= N) continue;
        int col = ctg * 16 + lr;
        float hv = bf2f(hh[(size_t)m * 64 + col]) + bf2f(hl[(size_t)m * 64 + col]);
        float rr = sigmoidf_(acc[mt][ctg][r] + bias[col]);
        float uu = sigmoidf_(acc[mt][ctg + 4][r] + bias[64 + col]);
        float cc = tanhf_(acc[mt][ctg + 8][r] + bias[128 + col] + rr * acch[mt][ctg][r]);
        float ho = uu * hv + (1.f - uu) * cc;
        if (outF) outF[(size_t)m * 64 + col] = ho;
        if (oh) {
          unsigned short hb = f2bf(ho);
          oh[(size_t)m * 64 + col] = hb;
          ol[(size_t)m * 64 + col] = f2bf(ho - bf2f(hb));
        }
      }
}

extern "C" void kernel_launch(void* const* d_in, const int* in_sizes, int n_in,
                              void* d_out, int out_size, void* d_ws, size_t ws_size,
                              hipStream_t stream) {
  const int*   toks  = (const int*)d_in[0];
  const int*   adj   = (const int*)d_in[1];
  const float* embed = (const float*)d_in[2];
  const float* projW = (const float*)d_in[3];
  const float* eW0   = (const float*)d_in[4];
  const float* eW1   = (const float*)d_in[5];
  const float* g0Wx  = (const float*)d_in[6];
  const float* g0Wh  = (const float*)d_in[7];
  const float* g0b   = (const float*)d_in[8];
  const float* g1Wx  = (const float*)d_in[9];
  const float* g1Wh  = (const float*)d_in[10];
  const float* g1b   = (const float*)d_in[11];
  float* out = (float*)d_out;

  int N = in_sizes[0] / 5;
  int E = in_sizes[1] / 8;
  size_t ND = (size_t)N * 64;

  char* p = (char*)d_ws;
  unsigned short* Htb     = (unsigned short*)p; p += 8 * ND * 2;   // 61.4 MB
  unsigned short* h_hi    = (unsigned short*)p; p += ND * 2;
  unsigned short* h_lo    = (unsigned short*)p; p += ND * 2;
  unsigned short* hinit_b = (unsigned short*)p; p += ND * 2;
  unsigned short* m_hi    = (unsigned short*)p; p += ND * 2;
  int* offsets = (int*)p; p += (size_t)(N + 64) * sizeof(int);
  int* cnt_cur = (int*)p; p += (size_t)(N + 64) * sizeof(int);   // counts, then cursor
  int* entries = (int*)p; p += (size_t)8 * E * sizeof(int);
  unsigned short* eW0f  = (unsigned short*)p; p += 65536 * 2;
  unsigned short* eW1f  = (unsigned short*)p; p += 65536 * 2;
  unsigned short* projf = (unsigned short*)p; p += 8192 * 2;
  unsigned short* g0xf  = (unsigned short*)p; p += 24576 * 2;
  unsigned short* g0hf  = (unsigned short*)p; p += 24576 * 2;
  unsigned short* g1xf  = (unsigned short*)p; p += 49152 * 2;
  unsigned short* g1hf  = (unsigned short*)p; p += 24576 * 2;
  if ((size_t)(p - (char*)d_ws) > ws_size) return;

  // init-phase aliases inside Htb (consumed before the first transform)
  unsigned short* emb_h = Htb;
  unsigned short* emb_l = Htb + ND;

  int g128 = (N + 127) / 128;
  int g4 = (N + 3) / 4;

  k_wprep_all<<<1024, 256, 0, stream>>>(eW0, eW1, projW, g0Wx, g0Wh, g1Wx, g1Wh,
                                        eW0f, eW1f, projf, g0xf, g0hf, g1xf, g1hf);
  hipMemsetAsync(cnt_cur, 0, (size_t)N * sizeof(int), stream);
  dim3 egrid((E + 255) / 256, 4);
  k_counts<<<egrid, 256, 0, stream>>>(adj, cnt_cur, E);
  k_embed<<<g4, 256, 0, stream>>>(toks, embed, emb_h, emb_l, N);
  k_proj<<<g128, 256, 0, stream>>>(emb_h, emb_l, projf, h_hi, h_lo, hinit_b, N);
  k_scan<<<1, 1024, 0, stream>>>(cnt_cur, offsets, cnt_cur, N);
  k_fill<<<egrid, 256, 0, stream>>>(adj, cnt_cur, entries, E, N);

  for (int it = 0; it < 8; ++it) {
    const unsigned short* ef = (it < 7) ? eW0f : eW1f;
    k_mm_t<<<dim3(g128, 4), 256, 0, stream>>>(h_hi, h_lo, ef, Htb, N);
    k_aggmax<<<g4, 256, 0, stream>>>(Htb, offsets, entries, m_hi, N);
    if (it < 7) {
      k_gru<2><<<g128, 256, 0, stream>>>(m_hi, nullptr, h_hi, h_lo,
                                         g0xf, g0hf, g0b,
                                         nullptr, h_hi, h_lo, N);
    } else {
      k_gru<4><<<g128, 256, 0, stream>>>(hinit_b, m_hi, h_hi, h_lo,
                                         g1xf, g1hf, g1b,
                                         out, nullptr, nullptr, N);
    }
  }
}